// Round 6
// baseline (326.276 us; speedup 1.0000x reference)
//
#include <hip/hip_runtime.h>
#include <math.h>

static constexpr int NN = 40000;   // nodes
static constexpr int NE = 640000;  // edges
static constexpr int DD = 128;     // feature dim
// H=4, DK=DE=32, P=1, n_layer=0

typedef __attribute__((ext_vector_type(8))) short short8;
typedef __attribute__((ext_vector_type(4))) float f32x4;

// ---------- helpers ----------
__device__ __forceinline__ unsigned short f2b(float f) {
  unsigned u = __float_as_uint(f);
  unsigned r = (u + 0x7FFFu + ((u >> 16) & 1u)) >> 16;  // RNE
  return (unsigned short)r;
}
__device__ __forceinline__ float b2f(unsigned short b) {
  return __uint_as_float(((unsigned)b) << 16);
}
__device__ __forceinline__ unsigned enc_f(float f) {
  unsigned u = __float_as_uint(f);
  return (u & 0x80000000u) ? ~u : (u | 0x80000000u);
}
__device__ __forceinline__ float dec_f(unsigned e) {
  unsigned u = (e & 0x80000000u) ? (e & 0x7FFFFFFFu) : ~e;
  return __uint_as_float(u);
}
// XOR swizzle for 256B-pitch LDS rows (row = byte>>8): flips 16B-chunk index
__device__ __forceinline__ int swz(int b) {
  return b ^ ((((b >> 8) & 7) << 4));
}
__device__ __forceinline__ float pdot(unsigned a, unsigned b) {
  float al = __uint_as_float(a << 16), ah = __uint_as_float(a & 0xFFFF0000u);
  float bl = __uint_as_float(b << 16), bh = __uint_as_float(b & 0xFFFF0000u);
  return al * bl + ah * bh;
}

// ---------------------------------------------------------------
// One-time weight transpose: W[mat] (H,1,3,D,32) fp32 -> Wt[(mat*3+t)][c][d] bf16
// ---------------------------------------------------------------
__global__ __launch_bounds__(256)
void wt_kernel(const float* __restrict__ Wq, const float* __restrict__ Wk,
               const float* __restrict__ Wv, unsigned short* __restrict__ Wt)
{
  __shared__ unsigned short tile[128 * 136];
  const int slab = blockIdx.x;
  const int mat = slab / 3, t = slab % 3;
  const float* W = (mat == 0) ? Wq : (mat == 1) ? Wk : Wv;
#pragma unroll
  for (int i = 0; i < 64; ++i) {
    int idx = i * 256 + threadIdx.x;       // over h(4) x d(128) x k(32)
    int h = idx >> 12, d = (idx >> 5) & 127, k = idx & 31;
    float v = W[(size_t)(((h * 3 + t) * 128 + d)) * 32 + k];
    tile[d * 136 + h * 32 + k] = f2b(v);   // tile[d][c]
  }
  __syncthreads();
#pragma unroll
  for (int i = 0; i < 8; ++i) {
    int idx = i * 256 + threadIdx.x;       // 2048 chunks of 8
    int c = idx >> 4, ch = idx & 15;
    union { unsigned short s[8]; uint4 v; } u;
#pragma unroll
    for (int j = 0; j < 8; ++j) u.s[j] = tile[(ch * 8 + j) * 136 + c];
    *(uint4*)&Wt[(size_t)slab * 16384 + c * 128 + ch * 8] = u.v;
  }
}

// ---------------------------------------------------------------
// LayerNorm: x fp32 [NN][128] -> Xn bf16 [NN][128]. One wave per row.
// ---------------------------------------------------------------
__global__ __launch_bounds__(256)
void ln_kernel(const float* __restrict__ x,
               const float* __restrict__ gamma, const float* __restrict__ beta,
               unsigned short* __restrict__ Xn)
{
  const int r = blockIdx.x * 4 + (threadIdx.x >> 6);
  const int lane = threadIdx.x & 63;
  float2 v = *(const float2*)(x + (size_t)r * DD + lane * 2);
  float s = v.x + v.y, ss = v.x * v.x + v.y * v.y;
#pragma unroll
  for (int off = 1; off < 64; off <<= 1) { s += __shfl_xor(s, off); ss += __shfl_xor(ss, off); }
  float mu = s * (1.f / 128.f);
  float rs = rsqrtf(ss * (1.f / 128.f) - mu * mu + 1e-5f);
  float2 g = *(const float2*)(gamma + lane * 2);
  float2 b = *(const float2*)(beta + lane * 2);
  unsigned lo = f2b((v.x - mu) * rs * g.x + b.x);
  unsigned hi = f2b((v.y - mu) * rs * g.y + b.y);
  *(unsigned*)(Xn + (size_t)r * DD + lane * 2) = lo | (hi << 16);
}

// ---------------------------------------------------------------
// QKV projection, bf16 MFMA. grid (9, 625), block 256 (4 waves).
// 64-row x 128-col tile per block; wave w owns rows w*16..+15.
// ---------------------------------------------------------------
__global__ __launch_bounds__(256)
void qkv_kernel(const unsigned short* __restrict__ Xn,
                const float* __restrict__ bq, const float* __restrict__ bk,
                const float* __restrict__ bv,
                const unsigned short* __restrict__ Wt,
                unsigned short* __restrict__ Qo, unsigned short* __restrict__ Ko,
                unsigned short* __restrict__ Vo)
{
  __shared__ unsigned char xs[16384];  // 64 rows x 256B (swizzled)
  __shared__ unsigned char wt[32768];  // 128 c-rows x 256B (swizzled)
  const int tid = threadIdx.x;
  const int lane = tid & 63;
  const int w = tid >> 6;
  const int l15 = lane & 15, kh = lane >> 4;
  const int combo = blockIdx.x;
  const int n0 = blockIdx.y * 64;
  const int mat = combo / 3, t = combo % 3;
  const float* B = (mat == 0) ? bq : (mat == 1) ? bk : bv;
  unsigned short* O = (mat == 0) ? Qo : (mat == 1) ? Ko : Vo;

  // ---- stage Wt slab (32KB) ----
#pragma unroll
  for (int i = 0; i < 8; ++i) {
    int idx = i * 256 + tid;
    int rr = idx >> 4, ch = idx & 15;
    uint4 d4 = *(const uint4*)(Wt + (size_t)combo * 16384 + rr * 128 + ch * 8);
    *(uint4*)(wt + swz(rr * 256 + ch * 16)) = d4;
  }
  // ---- stage Xn tile (16KB) ----
#pragma unroll
  for (int i = 0; i < 4; ++i) {
    int idx = i * 256 + tid;
    int rr = idx >> 4, ch = idx & 15;
    uint4 d4 = *(const uint4*)(Xn + (size_t)(n0 + rr) * DD + ch * 8);
    *(uint4*)(xs + swz(rr * 256 + ch * 16)) = d4;
  }

  // ---- init acc with bias ----
  f32x4 acc[8];
#pragma unroll
  for (int ct = 0; ct < 8; ++ct) {
    int cc = ct * 16 + l15;
    float bb = B[((cc >> 5) * 3 + t) * 32 + (cc & 31)];
    f32x4 bi = {bb, bb, bb, bb};
    acc[ct] = bi;
  }
  __syncthreads();

  // ---- MFMA: 4 k-steps x 8 col-tiles ----
#pragma unroll
  for (int ks = 0; ks < 4; ++ks) {
    short8 a0 = *(const short8*)(xs + swz((w * 16 + l15) * 256 + ks * 64 + kh * 16));
#pragma unroll
    for (int ct = 0; ct < 8; ++ct) {
      short8 bf = *(const short8*)(wt + swz((ct * 16 + l15) * 256 + ks * 64 + kh * 16));
      acc[ct] = __builtin_amdgcn_mfma_f32_16x16x32_bf16(a0, bf, acc[ct], 0, 0, 0);
    }
  }

  // ---- epilogue: repack own rows via LDS (wave-private region) ----
#pragma unroll
  for (int ct = 0; ct < 8; ++ct)
#pragma unroll
    for (int rg = 0; rg < 4; ++rg) {
      int rr = w * 16 + kh * 4 + rg;
      int cc = ct * 16 + l15;
      *(unsigned short*)(xs + swz(rr * 256 + cc * 2)) = f2b(acc[ct][rg]);
    }
  __syncthreads();
#pragma unroll
  for (int i = 0; i < 4; ++i) {
    int idx = i * 256 + tid;
    int rr = idx >> 4, ch = idx & 15;
    uint4 d4 = *(const uint4*)(xs + swz(rr * 256 + ch * 16));
    *(uint4*)(O + ((size_t)t * NN + n0 + rr) * DD + ch * 8) = d4;
  }
}

// ---------------------------------------------------------------
__global__ __launch_bounds__(256)
void hist_kernel(const int* __restrict__ ei, int* __restrict__ deg)
{
  int e = blockIdx.x * 256 + threadIdx.x;
  if (e < NE) atomicAdd(&deg[ei[NE + e]], 1);
}

// ---- two-level scan ----
__global__ __launch_bounds__(256)
void scan_part(const int* __restrict__ deg, int* __restrict__ base, int* __restrict__ bsum)
{
  const int b = blockIdx.x, tid = threadIdx.x;
  int i = b * 256 + tid;
  int v = (i < NN) ? deg[i] : 0;
  int xv = v;
#pragma unroll
  for (int off = 1; off < 64; off <<= 1) {
    int y = __shfl_up(xv, off);
    if ((tid & 63) >= off) xv += y;
  }
  __shared__ int wsum[4];
  if ((tid & 63) == 63) wsum[tid >> 6] = xv;
  __syncthreads();
  int add = 0;
  if (tid >= 64)  add += wsum[0];
  if (tid >= 128) add += wsum[1];
  if (tid >= 192) add += wsum[2];
  xv += add;
  if (i < NN) base[i] = xv - v;   // local exclusive
  if (tid == 255) bsum[b] = xv;
}

__global__ __launch_bounds__(64)
void scan_mid(const int* __restrict__ bsum, int* __restrict__ boff, int nb)
{
  __shared__ int carry;
  if (threadIdx.x == 0) carry = 0;
  __syncthreads();
  for (int s = 0; s < nb; s += 64) {
    int i = s + threadIdx.x;
    int v = (i < nb) ? bsum[i] : 0;
    int xv = v;
#pragma unroll
    for (int off = 1; off < 64; off <<= 1) {
      int y = __shfl_up(xv, off);
      if (threadIdx.x >= (unsigned)off) xv += y;
    }
    int c = carry;
    if (i < nb) boff[i] = c + xv - v;
    __syncthreads();
    if (threadIdx.x == 63) carry = c + xv;
    __syncthreads();
  }
}

__global__ __launch_bounds__(256)
void scan_add(int* __restrict__ base, const int* __restrict__ boff)
{
  int i = blockIdx.x * 256 + threadIdx.x;
  if (i < NN) base[i] += boff[blockIdx.x];
  if (i == 0) base[NN] = NE;
}

// ---------------------------------------------------------------
// Scatter edges into CSR slots: code=(src|t<<16), dstA, decay.
// ---------------------------------------------------------------
__global__ __launch_bounds__(256)
void scatter_kernel(const int* __restrict__ ei, const float* __restrict__ ev,
                    const float* __restrict__ m1, const float* __restrict__ m2,
                    const int* __restrict__ base, int* __restrict__ fill,
                    int* __restrict__ code, int* __restrict__ dstA,
                    float* __restrict__ dec)
{
  int e = blockIdx.x * 256 + threadIdx.x;
  int src = ei[e];
  int dst = ei[NE + e];
  int t = (m1[e] > 0.5f) ? 1 : ((m2[e] > 0.5f) ? 2 : 0);
  float av = fabsf(ev[e]);
  float decay = exp2f(-0.15200309344504995f * av);      // 0.9^|v|
  int slot = base[dst] + atomicAdd(&fill[dst], 1);
  code[slot] = src | (t << 16);
  dstA[slot] = dst;
  dec[slot]  = decay;
}

// ---------------------------------------------------------------
// Attention scores in CSR (dst-sorted) order. 4 threads/slot (one per head).
// Q gathers hit L1 (consecutive slots share dst). Global max via atomicMax.
// ---------------------------------------------------------------
__global__ __launch_bounds__(256)
void att_kernel(const int* __restrict__ code, const int* __restrict__ dstA,
                const float* __restrict__ dec,
                const unsigned short* __restrict__ Q, const unsigned short* __restrict__ K,
                float* __restrict__ attp, unsigned* __restrict__ gmaxU)
{
  __shared__ unsigned smax[4];
  const int tid = threadIdx.x;
  if (tid < 4) smax[tid] = 0u;
  __syncthreads();

  const int g = blockIdx.x * 256 + tid;
  const int slot = g >> 2;
  const int h = g & 3;
  const int cd = code[slot];
  const int src = cd & 0xFFFF;
  const int t = cd >> 16;
  const int dst = dstA[slot];

  const unsigned short* qr = Q + ((size_t)t * NN + dst) * DD + h * 32;
  const unsigned short* kr = K + ((size_t)t * NN + src) * DD + h * 32;
  float dot = 0.f;
#pragma unroll
  for (int i = 0; i < 4; ++i) {
    uint4 a = ((const uint4*)qr)[i];
    uint4 b = ((const uint4*)kr)[i];
    dot += pdot(a.x, b.x) + pdot(a.y, b.y) + pdot(a.z, b.z) + pdot(a.w, b.w);
  }
  float ap = dot * 0.17677669529663687f * dec[slot];    // /sqrt(32)*decay
  attp[(size_t)slot * 4 + h] = ap;

  float m = ap;
  m = fmaxf(m, __shfl_xor(m, 4));
  m = fmaxf(m, __shfl_xor(m, 8));
  m = fmaxf(m, __shfl_xor(m, 16));
  m = fmaxf(m, __shfl_xor(m, 32));
  if ((tid & 63) < 4) atomicMax(&smax[h], enc_f(m));
  __syncthreads();
  if (tid < 4) atomicMax(&gmaxU[tid], smax[tid]);
}

// ---------------------------------------------------------------
// Per-node aggregation. bf16 V.
// ---------------------------------------------------------------
__global__ __launch_bounds__(128)
void node_kernel(const float* __restrict__ x, const unsigned short* __restrict__ V,
                 const float* __restrict__ attp, const int* __restrict__ code,
                 const int* __restrict__ base, const unsigned* __restrict__ gmaxU,
                 float* __restrict__ out)
{
  const int n = blockIdx.x;
  const int c = threadIdx.x;
  const int h = c >> 5;
  const float mx = dec_f(gmaxU[h]);
  const int b0 = base[n], b1 = base[n + 1];
  float acc = 0.f, den = 0.f;
  for (int j = b0; j < b1; ++j) {
    int cd = code[j];
    int s = cd & 0xFFFF;
    int t = cd >> 16;
    float a = __expf(attp[(size_t)j * 4 + h] - mx);
    den += a;
    acc += a * b2f(V[((size_t)t * NN + s) * DD + c]);
  }
  float z = acc / (den + 1e-16f);
  float g = 0.5f * z * (1.0f + erff(z * 0.70710678118654752f));
  out[(size_t)n * DD + c] = x[(size_t)n * DD + c] + g;
}

// ---------------------------------------------------------------
extern "C" void kernel_launch(void* const* d_in, const int* in_sizes, int n_in,
                              void* d_out, int out_size, void* d_ws, size_t ws_size,
                              hipStream_t stream)
{
  const float* x     = (const float*)d_in[0];
  const int*   ei    = (const int*)d_in[1];
  const float* ev    = (const float*)d_in[2];
  const float* m1    = (const float*)d_in[5];  // diff_time_same_var -> t=1
  const float* m2    = (const float*)d_in[6];  // diff_time_diff_var -> t=2
  const float* gamma = (const float*)d_in[8];
  const float* beta  = (const float*)d_in[9];
  const float* Wq    = (const float*)d_in[10];
  const float* bq    = (const float*)d_in[11];
  const float* Wk    = (const float*)d_in[12];
  const float* bk    = (const float*)d_in[13];
  const float* Wv    = (const float*)d_in[14];
  const float* bv    = (const float*)d_in[15];
  float* out = (float*)d_out;

  // ---- workspace layout ----
  unsigned short* Q  = (unsigned short*)d_ws;        // 3*NN*128 bf16
  unsigned short* Kb = Q  + (size_t)3 * NN * DD;
  unsigned short* Vb = Kb + (size_t)3 * NN * DD;
  unsigned short* Xn = Vb + (size_t)3 * NN * DD;     // NN*128 bf16
  unsigned short* Wt = Xn + (size_t)NN * DD;         // 9*16384 bf16
  float* attp = (float*)(Wt + 9 * 16384);            // NE*4 f32
  int*   code = (int*)(attp + (size_t)NE * 4);       // NE
  int*   dstA = code + NE;                           // NE
  float* dec  = (float*)(dstA + NE);                 // NE
  int*   deg  = (int*)(dec + NE);                    // NN
  int*   fill = deg + NN;                            // NN
  unsigned* gmaxU = (unsigned*)(fill + NN);          // 4
  int*   base = (int*)(gmaxU + 4);                   // NN+1
  int*   bsum = base + NN + 1;                       // 157
  int*   boff = bsum + 157;                          // 157

  hipMemsetAsync(deg, 0, ((size_t)2 * NN + 4) * sizeof(int), stream);  // deg+fill+gmaxU

  wt_kernel<<<9, 256, 0, stream>>>(Wq, Wk, Wv, Wt);
  ln_kernel<<<NN / 4, 256, 0, stream>>>(x, gamma, beta, Xn);
  qkv_kernel<<<dim3(9, NN / 64), 256, 0, stream>>>(Xn, bq, bk, bv, Wt, Q, Kb, Vb);
  hist_kernel<<<NE / 256, 256, 0, stream>>>(ei, deg);
  scan_part<<<157, 256, 0, stream>>>(deg, base, bsum);
  scan_mid<<<1, 64, 0, stream>>>(bsum, boff, 157);
  scan_add<<<157, 256, 0, stream>>>(base, boff);
  scatter_kernel<<<NE / 256, 256, 0, stream>>>(ei, ev, m1, m2, base, fill, code, dstA, dec);
  att_kernel<<<(NE * 4) / 256, 256, 0, stream>>>(code, dstA, dec, Q, Kb, attp, gmaxU);
  node_kernel<<<NN, 128, 0, stream>>>(x, Vb, attp, code, base, gmaxU, out);
}

// Round 7
// 228.448 us; speedup vs baseline: 1.4282x; 1.4282x over previous
//
#include <hip/hip_runtime.h>
#include <math.h>

static constexpr int NN = 40000;   // nodes
static constexpr int NE = 640000;  // edges
static constexpr int DD = 128;     // feature dim
// H=4, DK=DE=32, P=1, n_layer=0

typedef __attribute__((ext_vector_type(8))) short short8;
typedef __attribute__((ext_vector_type(4))) float f32x4;

// ---------- helpers ----------
__device__ __forceinline__ unsigned short f2b(float f) {
  unsigned u = __float_as_uint(f);
  unsigned r = (u + 0x7FFFu + ((u >> 16) & 1u)) >> 16;  // RNE
  return (unsigned short)r;
}
// XOR swizzle for 256B-pitch LDS rows (row = byte>>8): flips 16B-chunk index
__device__ __forceinline__ int swz(int b) {
  return b ^ ((((b >> 8) & 7) << 4));
}
__device__ __forceinline__ float pdot(unsigned a, unsigned b) {
  float al = __uint_as_float(a << 16), ah = __uint_as_float(a & 0xFFFF0000u);
  float bl = __uint_as_float(b << 16), bh = __uint_as_float(b & 0xFFFF0000u);
  return al * bl + ah * bh;
}

// ---------------------------------------------------------------
// One-time weight transpose: W[mat] (H,1,3,D,32) fp32 -> Wt[(mat*3+t)][c][d] bf16
// ---------------------------------------------------------------
__global__ __launch_bounds__(256)
void wt_kernel(const float* __restrict__ Wq, const float* __restrict__ Wk,
               const float* __restrict__ Wv, unsigned short* __restrict__ Wt)
{
  __shared__ unsigned short tile[128 * 136];
  const int slab = blockIdx.x;
  const int mat = slab / 3, t = slab % 3;
  const float* W = (mat == 0) ? Wq : (mat == 1) ? Wk : Wv;
#pragma unroll
  for (int i = 0; i < 64; ++i) {
    int idx = i * 256 + threadIdx.x;       // over h(4) x d(128) x k(32)
    int h = idx >> 12, d = (idx >> 5) & 127, k = idx & 31;
    float v = W[(size_t)(((h * 3 + t) * 128 + d)) * 32 + k];
    tile[d * 136 + h * 32 + k] = f2b(v);   // tile[d][c]
  }
  __syncthreads();
#pragma unroll
  for (int i = 0; i < 8; ++i) {
    int idx = i * 256 + threadIdx.x;       // 2048 chunks of 8
    int c = idx >> 4, ch = idx & 15;
    union { unsigned short s[8]; uint4 v; } u;
#pragma unroll
    for (int j = 0; j < 8; ++j) u.s[j] = tile[(ch * 8 + j) * 136 + c];
    *(uint4*)&Wt[(size_t)slab * 16384 + c * 128 + ch * 8] = u.v;
  }
}

// ---------------------------------------------------------------
// LayerNorm: x fp32 [NN][128] -> Xn bf16 [NN][128]. One wave per row.
// ---------------------------------------------------------------
__global__ __launch_bounds__(256)
void ln_kernel(const float* __restrict__ x,
               const float* __restrict__ gamma, const float* __restrict__ beta,
               unsigned short* __restrict__ Xn)
{
  const int r = blockIdx.x * 4 + (threadIdx.x >> 6);
  const int lane = threadIdx.x & 63;
  float2 v = *(const float2*)(x + (size_t)r * DD + lane * 2);
  float s = v.x + v.y, ss = v.x * v.x + v.y * v.y;
#pragma unroll
  for (int off = 1; off < 64; off <<= 1) { s += __shfl_xor(s, off); ss += __shfl_xor(ss, off); }
  float mu = s * (1.f / 128.f);
  float rs = rsqrtf(ss * (1.f / 128.f) - mu * mu + 1e-5f);
  float2 g = *(const float2*)(gamma + lane * 2);
  float2 b = *(const float2*)(beta + lane * 2);
  unsigned lo = f2b((v.x - mu) * rs * g.x + b.x);
  unsigned hi = f2b((v.y - mu) * rs * g.y + b.y);
  *(unsigned*)(Xn + (size_t)r * DD + lane * 2) = lo | (hi << 16);
}

// ---------------------------------------------------------------
// QKV projection, bf16 MFMA. grid (9, 625), block 256 (4 waves).
// 64-row x 128-col tile per block; wave w owns rows w*16..+15.
// ---------------------------------------------------------------
__global__ __launch_bounds__(256)
void qkv_kernel(const unsigned short* __restrict__ Xn,
                const float* __restrict__ bq, const float* __restrict__ bk,
                const float* __restrict__ bv,
                const unsigned short* __restrict__ Wt,
                unsigned short* __restrict__ Qo, unsigned short* __restrict__ Ko,
                unsigned short* __restrict__ Vo)
{
  __shared__ unsigned char xs[16384];  // 64 rows x 256B (swizzled)
  __shared__ unsigned char wt[32768];  // 128 c-rows x 256B (swizzled)
  const int tid = threadIdx.x;
  const int lane = tid & 63;
  const int w = tid >> 6;
  const int l15 = lane & 15, kh = lane >> 4;
  const int combo = blockIdx.x;
  const int n0 = blockIdx.y * 64;
  const int mat = combo / 3, t = combo % 3;
  const float* B = (mat == 0) ? bq : (mat == 1) ? bk : bv;
  unsigned short* O = (mat == 0) ? Qo : (mat == 1) ? Ko : Vo;

  // ---- stage Wt slab (32KB) ----
#pragma unroll
  for (int i = 0; i < 8; ++i) {
    int idx = i * 256 + tid;
    int rr = idx >> 4, ch = idx & 15;
    uint4 d4 = *(const uint4*)(Wt + (size_t)combo * 16384 + rr * 128 + ch * 8);
    *(uint4*)(wt + swz(rr * 256 + ch * 16)) = d4;
  }
  // ---- stage Xn tile (16KB) ----
#pragma unroll
  for (int i = 0; i < 4; ++i) {
    int idx = i * 256 + tid;
    int rr = idx >> 4, ch = idx & 15;
    uint4 d4 = *(const uint4*)(Xn + (size_t)(n0 + rr) * DD + ch * 8);
    *(uint4*)(xs + swz(rr * 256 + ch * 16)) = d4;
  }

  // ---- init acc with bias ----
  f32x4 acc[8];
#pragma unroll
  for (int ct = 0; ct < 8; ++ct) {
    int cc = ct * 16 + l15;
    float bb = B[((cc >> 5) * 3 + t) * 32 + (cc & 31)];
    f32x4 bi = {bb, bb, bb, bb};
    acc[ct] = bi;
  }
  __syncthreads();

  // ---- MFMA: 4 k-steps x 8 col-tiles ----
#pragma unroll
  for (int ks = 0; ks < 4; ++ks) {
    short8 a0 = *(const short8*)(xs + swz((w * 16 + l15) * 256 + ks * 64 + kh * 16));
#pragma unroll
    for (int ct = 0; ct < 8; ++ct) {
      short8 bf = *(const short8*)(wt + swz((ct * 16 + l15) * 256 + ks * 64 + kh * 16));
      acc[ct] = __builtin_amdgcn_mfma_f32_16x16x32_bf16(a0, bf, acc[ct], 0, 0, 0);
    }
  }

  // ---- epilogue: repack own rows via LDS (wave-private region) ----
#pragma unroll
  for (int ct = 0; ct < 8; ++ct)
#pragma unroll
    for (int rg = 0; rg < 4; ++rg) {
      int rr = w * 16 + kh * 4 + rg;
      int cc = ct * 16 + l15;
      *(unsigned short*)(xs + swz(rr * 256 + cc * 2)) = f2b(acc[ct][rg]);
    }
  __syncthreads();
#pragma unroll
  for (int i = 0; i < 4; ++i) {
    int idx = i * 256 + tid;
    int rr = idx >> 4, ch = idx & 15;
    uint4 d4 = *(const uint4*)(xs + swz(rr * 256 + ch * 16));
    *(uint4*)(O + ((size_t)t * NN + n0 + rr) * DD + ch * 8) = d4;
  }
}

// ---------------------------------------------------------------
__global__ __launch_bounds__(256)
void hist_kernel(const int* __restrict__ ei, int* __restrict__ deg)
{
  int e = blockIdx.x * 256 + threadIdx.x;
  if (e < NE) atomicAdd(&deg[ei[NE + e]], 1);
}

// ---- two-level scan ----
__global__ __launch_bounds__(256)
void scan_part(const int* __restrict__ deg, int* __restrict__ base, int* __restrict__ bsum)
{
  const int b = blockIdx.x, tid = threadIdx.x;
  int i = b * 256 + tid;
  int v = (i < NN) ? deg[i] : 0;
  int xv = v;
#pragma unroll
  for (int off = 1; off < 64; off <<= 1) {
    int y = __shfl_up(xv, off);
    if ((tid & 63) >= off) xv += y;
  }
  __shared__ int wsum[4];
  if ((tid & 63) == 63) wsum[tid >> 6] = xv;
  __syncthreads();
  int add = 0;
  if (tid >= 64)  add += wsum[0];
  if (tid >= 128) add += wsum[1];
  if (tid >= 192) add += wsum[2];
  xv += add;
  if (i < NN) base[i] = xv - v;   // local exclusive
  if (tid == 255) bsum[b] = xv;
}

__global__ __launch_bounds__(64)
void scan_mid(const int* __restrict__ bsum, int* __restrict__ boff, int nb)
{
  __shared__ int carry;
  if (threadIdx.x == 0) carry = 0;
  __syncthreads();
  for (int s = 0; s < nb; s += 64) {
    int i = s + threadIdx.x;
    int v = (i < nb) ? bsum[i] : 0;
    int xv = v;
#pragma unroll
    for (int off = 1; off < 64; off <<= 1) {
      int y = __shfl_up(xv, off);
      if (threadIdx.x >= (unsigned)off) xv += y;
    }
    int c = carry;
    if (i < nb) boff[i] = c + xv - v;
    __syncthreads();
    if (threadIdx.x == 63) carry = c + xv;
    __syncthreads();
  }
}

__global__ __launch_bounds__(256)
void scan_add(int* __restrict__ base, const int* __restrict__ boff)
{
  int i = blockIdx.x * 256 + threadIdx.x;
  if (i < NN) base[i] += boff[blockIdx.x];
  if (i == 0) base[NN] = NE;
}

// ---------------------------------------------------------------
// Scatter edges into CSR slots: esl[slot] = { src | t<<16, bits(decay) }.
// ---------------------------------------------------------------
__global__ __launch_bounds__(256)
void scatter_kernel(const int* __restrict__ ei, const float* __restrict__ ev,
                    const float* __restrict__ m1, const float* __restrict__ m2,
                    const int* __restrict__ base, int* __restrict__ fill,
                    int2* __restrict__ esl)
{
  int e = blockIdx.x * 256 + threadIdx.x;
  int src = ei[e];
  int dst = ei[NE + e];
  int t = (m1[e] > 0.5f) ? 1 : ((m2[e] > 0.5f) ? 2 : 0);
  float av = fabsf(ev[e]);
  float decay = exp2f(-0.15200309344504995f * av);      // 0.9^|v|
  int slot = base[dst] + atomicAdd(&fill[dst], 1);
  int2 v; v.x = src | (t << 16); v.y = __float_as_int(decay);
  esl[slot] = v;
}

// ---------------------------------------------------------------
// Fused per-node attention: scores + online softmax (per-node max) +
// V aggregation + residual + GeLU. One 128-thread block per node.
// Phase A: 4 threads/edge (one per head) compute QK dots.
// Phase B: 4 edge-groups x 32 lanes accumulate V (4 comps/lane).
// ---------------------------------------------------------------
__global__ __launch_bounds__(128)
void agg_kernel(const float* __restrict__ x,
                const unsigned short* __restrict__ Q,
                const unsigned short* __restrict__ K,
                const unsigned short* __restrict__ V,
                const int2* __restrict__ esl, const int* __restrict__ base,
                float* __restrict__ out)
{
  const int n = blockIdx.x;
  const int tid = threadIdx.x;
  const int wv = tid >> 6;
  const int b0 = base[n], b1 = base[n + 1];

  __shared__ unsigned short qs[3 * 128];   // Q rows for t=0..2
  __shared__ int2  ecs[32];                // chunk edge codes
  __shared__ float as_[32][4];             // chunk softmax numerators
  __shared__ float redm[2][4], redd[2][4]; // cross-wave reduce
  __shared__ float mrun[4], drun[4], fac[4], mnew[4];
  __shared__ float accred[4][128];

  if (tid < 96) {
    int t = tid >> 5, p = tid & 31;
    *(uint2*)&qs[t * 128 + p * 4] = *(const uint2*)(Q + ((size_t)t * NN + n) * DD + p * 4);
  }
  if (tid < 4) { mrun[tid] = -3e38f; drun[tid] = 0.f; }

  const int eA = tid >> 2, h = tid & 3;    // phase-A role
  const int g = tid >> 5, l32 = tid & 31;  // phase-B role
  const int hB = l32 >> 3;                 // head of this lane's components
  float acc[4] = {0.f, 0.f, 0.f, 0.f};

  __syncthreads();

  for (int cs = b0; cs < b1; cs += 32) {
    int j = cs + eA;
    bool act = (j < b1);
    float s = -3e38f;
    int2 ec = make_int2(0, 0);
    if (act) {
      ec = esl[j];
      int src = ec.x & 0xFFFF, t = ec.x >> 16;
      const unsigned short* kr = K + ((size_t)t * NN + src) * DD + h * 32;
      const unsigned short* qr = qs + t * 128 + h * 32;
      float dot = 0.f;
#pragma unroll
      for (int i = 0; i < 4; ++i) {
        uint4 a4 = ((const uint4*)kr)[i];
        uint4 q4 = ((const uint4*)qr)[i];
        dot += pdot(a4.x, q4.x) + pdot(a4.y, q4.y) + pdot(a4.z, q4.z) + pdot(a4.w, q4.w);
      }
      s = dot * 0.17677669529663687f * __int_as_float(ec.y);
    }
    if (h == 0) ecs[eA] = ec;
    // per-head chunk max (edges strided by 4 within wave; xor 4..32)
    float m = s;
    m = fmaxf(m, __shfl_xor(m, 4));
    m = fmaxf(m, __shfl_xor(m, 8));
    m = fmaxf(m, __shfl_xor(m, 16));
    m = fmaxf(m, __shfl_xor(m, 32));
    if ((tid & 63) < 4) redm[wv][tid & 3] = m;
    __syncthreads();
    if (tid < 4) {
      float mc = fmaxf(redm[0][tid], redm[1][tid]);
      float mn = fmaxf(mrun[tid], mc);
      fac[tid]  = __expf(mrun[tid] - mn);   // first chunk: exp(-inf)=0
      mnew[tid] = mn;
      mrun[tid] = mn;
    }
    __syncthreads();
    float a = act ? __expf(s - mnew[h]) : 0.f;
    as_[eA][h] = a;
    float d = a;
    d += __shfl_xor(d, 4);
    d += __shfl_xor(d, 8);
    d += __shfl_xor(d, 16);
    d += __shfl_xor(d, 32);
    if ((tid & 63) < 4) redd[wv][tid & 3] = d;
    // rescale running accumulators
    float f = fac[hB];
    acc[0] *= f; acc[1] *= f; acc[2] *= f; acc[3] *= f;
    __syncthreads();
    if (tid < 4) drun[tid] = drun[tid] * fac[tid] + redd[0][tid] + redd[1][tid];
    // phase B: V accumulation (4 edges in parallel, 8B/lane)
#pragma unroll
    for (int e = g; e < 32; e += 4) {
      float aw = as_[e][hB];
      if (aw > 0.f) {
        int cd = ecs[e].x;
        int src = cd & 0xFFFF, t = cd >> 16;
        uint2 v2 = *(const uint2*)(V + ((size_t)t * NN + src) * DD + l32 * 4);
        acc[0] += aw * __uint_as_float(v2.x << 16);
        acc[1] += aw * __uint_as_float(v2.x & 0xFFFF0000u);
        acc[2] += aw * __uint_as_float(v2.y << 16);
        acc[3] += aw * __uint_as_float(v2.y & 0xFFFF0000u);
      }
    }
    __syncthreads();   // protect ecs/as_/redm before next chunk
  }

  // combine the 4 edge-group partials
#pragma unroll
  for (int k2 = 0; k2 < 4; ++k2) accred[g][l32 * 4 + k2] = acc[k2];
  __syncthreads();
  float z = accred[0][tid] + accred[1][tid] + accred[2][tid] + accred[3][tid];
  z /= (drun[tid >> 5] + 1e-16f);
  float gl = 0.5f * z * (1.0f + erff(z * 0.70710678118654752f));
  out[(size_t)n * DD + tid] = x[(size_t)n * DD + tid] + gl;
}

// ---------------------------------------------------------------
extern "C" void kernel_launch(void* const* d_in, const int* in_sizes, int n_in,
                              void* d_out, int out_size, void* d_ws, size_t ws_size,
                              hipStream_t stream)
{
  const float* x     = (const float*)d_in[0];
  const int*   ei    = (const int*)d_in[1];
  const float* ev    = (const float*)d_in[2];
  const float* m1    = (const float*)d_in[5];  // diff_time_same_var -> t=1
  const float* m2    = (const float*)d_in[6];  // diff_time_diff_var -> t=2
  const float* gamma = (const float*)d_in[8];
  const float* beta  = (const float*)d_in[9];
  const float* Wq    = (const float*)d_in[10];
  const float* bq    = (const float*)d_in[11];
  const float* Wk    = (const float*)d_in[12];
  const float* bk    = (const float*)d_in[13];
  const float* Wv    = (const float*)d_in[14];
  const float* bv    = (const float*)d_in[15];
  float* out = (float*)d_out;

  // ---- workspace layout ----
  unsigned short* Q  = (unsigned short*)d_ws;        // 3*NN*128 bf16
  unsigned short* Kb = Q  + (size_t)3 * NN * DD;
  unsigned short* Vb = Kb + (size_t)3 * NN * DD;
  unsigned short* Xn = Vb + (size_t)3 * NN * DD;     // NN*128 bf16
  unsigned short* Wt = Xn + (size_t)NN * DD;         // 9*16384 bf16
  int2*  esl  = (int2*)(Wt + 9 * 16384);             // NE int2 (8B-aligned)
  int*   deg  = (int*)(esl + NE);                    // NN
  int*   fill = deg + NN;                            // NN
  int*   base = fill + NN;                           // NN+1
  int*   bsum = base + NN + 1;                       // 157
  int*   boff = bsum + 157;                          // 157

  hipMemsetAsync(deg, 0, (size_t)2 * NN * sizeof(int), stream);  // deg + fill

  wt_kernel<<<9, 256, 0, stream>>>(Wq, Wk, Wv, Wt);
  ln_kernel<<<NN / 4, 256, 0, stream>>>(x, gamma, beta, Xn);
  qkv_kernel<<<dim3(9, NN / 64), 256, 0, stream>>>(Xn, bq, bk, bv, Wt, Q, Kb, Vb);
  hist_kernel<<<NE / 256, 256, 0, stream>>>(ei, deg);
  scan_part<<<157, 256, 0, stream>>>(deg, base, bsum);
  scan_mid<<<1, 64, 0, stream>>>(bsum, boff, 157);
  scan_add<<<157, 256, 0, stream>>>(base, boff);
  scatter_kernel<<<NE / 256, 256, 0, stream>>>(ei, ev, m1, m2, base, fill, esl);
  agg_kernel<<<NN, 128, 0, stream>>>(x, Q, Kb, Vb, esl, base, out);
}

// Round 9
// 212.227 us; speedup vs baseline: 1.5374x; 1.0764x over previous
//
#include <hip/hip_runtime.h>
#include <math.h>

static constexpr int NN = 40000;   // nodes
static constexpr int NE = 640000;  // edges
static constexpr int DD = 128;     // feature dim
// H=4, DK=DE=32, P=1, n_layer=0

typedef __attribute__((ext_vector_type(8))) short short8;
typedef __attribute__((ext_vector_type(4))) float f32x4;

// ---------- helpers ----------
__device__ __forceinline__ unsigned short f2b(float f) {
  unsigned u = __float_as_uint(f);
  unsigned r = (u + 0x7FFFu + ((u >> 16) & 1u)) >> 16;  // RNE
  return (unsigned short)r;
}
// XOR swizzle for 256B-pitch LDS rows (row = byte>>8): flips 16B-chunk index
__device__ __forceinline__ int swz(int b) {
  return b ^ ((((b >> 8) & 7) << 4));
}
__device__ __forceinline__ float pdot(unsigned a, unsigned b) {
  float al = __uint_as_float(a << 16), ah = __uint_as_float(a & 0xFFFF0000u);
  float bl = __uint_as_float(b << 16), bh = __uint_as_float(b & 0xFFFF0000u);
  return al * bl + ah * bh;
}

// ---------------------------------------------------------------
// One-time weight transpose: W[mat] (H,1,3,D,32) fp32 -> Wt[(mat*3+t)][c][d] bf16
// ---------------------------------------------------------------
__global__ __launch_bounds__(256)
void wt_kernel(const float* __restrict__ Wq, const float* __restrict__ Wk,
               const float* __restrict__ Wv, unsigned short* __restrict__ Wt)
{
  __shared__ unsigned short tile[128 * 136];
  const int slab = blockIdx.x;
  const int mat = slab / 3, t = slab % 3;
  const float* W = (mat == 0) ? Wq : (mat == 1) ? Wk : Wv;
#pragma unroll
  for (int i = 0; i < 64; ++i) {
    int idx = i * 256 + threadIdx.x;       // over h(4) x d(128) x k(32)
    int h = idx >> 12, d = (idx >> 5) & 127, k = idx & 31;
    float v = W[(size_t)(((h * 3 + t) * 128 + d)) * 32 + k];
    tile[d * 136 + h * 32 + k] = f2b(v);   // tile[d][c]
  }
  __syncthreads();
#pragma unroll
  for (int i = 0; i < 8; ++i) {
    int idx = i * 256 + threadIdx.x;       // 2048 chunks of 8
    int c = idx >> 4, ch = idx & 15;
    union { unsigned short s[8]; uint4 v; } u;
#pragma unroll
    for (int j = 0; j < 8; ++j) u.s[j] = tile[(ch * 8 + j) * 136 + c];
    *(uint4*)&Wt[(size_t)slab * 16384 + c * 128 + ch * 8] = u.v;
  }
}

// ---------------------------------------------------------------
// LayerNorm: x fp32 [NN][128] -> Xn bf16 [NN][128]. One wave per row.
// ---------------------------------------------------------------
__global__ __launch_bounds__(256)
void ln_kernel(const float* __restrict__ x,
               const float* __restrict__ gamma, const float* __restrict__ beta,
               unsigned short* __restrict__ Xn)
{
  const int r = blockIdx.x * 4 + (threadIdx.x >> 6);
  const int lane = threadIdx.x & 63;
  float2 v = *(const float2*)(x + (size_t)r * DD + lane * 2);
  float s = v.x + v.y, ss = v.x * v.x + v.y * v.y;
#pragma unroll
  for (int off = 1; off < 64; off <<= 1) { s += __shfl_xor(s, off); ss += __shfl_xor(ss, off); }
  float mu = s * (1.f / 128.f);
  float rs = rsqrtf(ss * (1.f / 128.f) - mu * mu + 1e-5f);
  float2 g = *(const float2*)(gamma + lane * 2);
  float2 b = *(const float2*)(beta + lane * 2);
  unsigned lo = f2b((v.x - mu) * rs * g.x + b.x);
  unsigned hi = f2b((v.y - mu) * rs * g.y + b.y);
  *(unsigned*)(Xn + (size_t)r * DD + lane * 2) = lo | (hi << 16);
}

// ---------------------------------------------------------------
// QKV projection, bf16 MFMA. grid (9, 625), block 256 (4 waves).
// 64-row x 128-col tile per block; wave w owns rows w*16..+15.
// ---------------------------------------------------------------
__global__ __launch_bounds__(256)
void qkv_kernel(const unsigned short* __restrict__ Xn,
                const float* __restrict__ bq, const float* __restrict__ bk,
                const float* __restrict__ bv,
                const unsigned short* __restrict__ Wt,
                unsigned short* __restrict__ Qo, unsigned short* __restrict__ Ko,
                unsigned short* __restrict__ Vo)
{
  __shared__ unsigned char xs[16384];  // 64 rows x 256B (swizzled)
  __shared__ unsigned char wt[32768];  // 128 c-rows x 256B (swizzled)
  const int tid = threadIdx.x;
  const int lane = tid & 63;
  const int w = tid >> 6;
  const int l15 = lane & 15, kh = lane >> 4;
  const int combo = blockIdx.x;
  const int n0 = blockIdx.y * 64;
  const int mat = combo / 3, t = combo % 3;
  const float* B = (mat == 0) ? bq : (mat == 1) ? bk : bv;
  unsigned short* O = (mat == 0) ? Qo : (mat == 1) ? Ko : Vo;

  // ---- stage Wt slab (32KB) ----
#pragma unroll
  for (int i = 0; i < 8; ++i) {
    int idx = i * 256 + tid;
    int rr = idx >> 4, ch = idx & 15;
    uint4 d4 = *(const uint4*)(Wt + (size_t)combo * 16384 + rr * 128 + ch * 8);
    *(uint4*)(wt + swz(rr * 256 + ch * 16)) = d4;
  }
  // ---- stage Xn tile (16KB) ----
#pragma unroll
  for (int i = 0; i < 4; ++i) {
    int idx = i * 256 + tid;
    int rr = idx >> 4, ch = idx & 15;
    uint4 d4 = *(const uint4*)(Xn + (size_t)(n0 + rr) * DD + ch * 8);
    *(uint4*)(xs + swz(rr * 256 + ch * 16)) = d4;
  }

  // ---- init acc with bias ----
  f32x4 acc[8];
#pragma unroll
  for (int ct = 0; ct < 8; ++ct) {
    int cc = ct * 16 + l15;
    float bb = B[((cc >> 5) * 3 + t) * 32 + (cc & 31)];
    f32x4 bi = {bb, bb, bb, bb};
    acc[ct] = bi;
  }
  __syncthreads();

  // ---- MFMA: 4 k-steps x 8 col-tiles ----
#pragma unroll
  for (int ks = 0; ks < 4; ++ks) {
    short8 a0 = *(const short8*)(xs + swz((w * 16 + l15) * 256 + ks * 64 + kh * 16));
#pragma unroll
    for (int ct = 0; ct < 8; ++ct) {
      short8 bf = *(const short8*)(wt + swz((ct * 16 + l15) * 256 + ks * 64 + kh * 16));
      acc[ct] = __builtin_amdgcn_mfma_f32_16x16x32_bf16(a0, bf, acc[ct], 0, 0, 0);
    }
  }

  // ---- epilogue: repack own rows via LDS (wave-private region) ----
#pragma unroll
  for (int ct = 0; ct < 8; ++ct)
#pragma unroll
    for (int rg = 0; rg < 4; ++rg) {
      int rr = w * 16 + kh * 4 + rg;
      int cc = ct * 16 + l15;
      *(unsigned short*)(xs + swz(rr * 256 + cc * 2)) = f2b(acc[ct][rg]);
    }
  __syncthreads();
#pragma unroll
  for (int i = 0; i < 4; ++i) {
    int idx = i * 256 + tid;
    int rr = idx >> 4, ch = idx & 15;
    uint4 d4 = *(const uint4*)(xs + swz(rr * 256 + ch * 16));
    *(uint4*)(O + ((size_t)t * NN + n0 + rr) * DD + ch * 8) = d4;
  }
}

// ---------------------------------------------------------------
__global__ __launch_bounds__(256)
void hist_kernel(const int* __restrict__ ei, int* __restrict__ deg)
{
  int e = blockIdx.x * 256 + threadIdx.x;
  if (e < NE) atomicAdd(&deg[ei[NE + e]], 1);
}

// ---- two-level scan ----
__global__ __launch_bounds__(256)
void scan_part(const int* __restrict__ deg, int* __restrict__ base, int* __restrict__ bsum)
{
  const int b = blockIdx.x, tid = threadIdx.x;
  int i = b * 256 + tid;
  int v = (i < NN) ? deg[i] : 0;
  int xv = v;
#pragma unroll
  for (int off = 1; off < 64; off <<= 1) {
    int y = __shfl_up(xv, off);
    if ((tid & 63) >= off) xv += y;
  }
  __shared__ int wsum[4];
  if ((tid & 63) == 63) wsum[tid >> 6] = xv;
  __syncthreads();
  int add = 0;
  if (tid >= 64)  add += wsum[0];
  if (tid >= 128) add += wsum[1];
  if (tid >= 192) add += wsum[2];
  xv += add;
  if (i < NN) base[i] = xv - v;   // local exclusive
  if (tid == 255) bsum[b] = xv;
}

__global__ __launch_bounds__(64)
void scan_mid(const int* __restrict__ bsum, int* __restrict__ boff, int nb)
{
  __shared__ int carry;
  if (threadIdx.x == 0) carry = 0;
  __syncthreads();
  for (int s = 0; s < nb; s += 64) {
    int i = s + threadIdx.x;
    int v = (i < nb) ? bsum[i] : 0;
    int xv = v;
#pragma unroll
    for (int off = 1; off < 64; off <<= 1) {
      int y = __shfl_up(xv, off);
      if (threadIdx.x >= (unsigned)off) xv += y;
    }
    int c = carry;
    if (i < nb) boff[i] = c + xv - v;
    __syncthreads();
    if (threadIdx.x == 63) carry = c + xv;
    __syncthreads();
  }
}

__global__ __launch_bounds__(256)
void scan_add(int* __restrict__ base, const int* __restrict__ boff)
{
  int i = blockIdx.x * 256 + threadIdx.x;
  if (i < NN) base[i] += boff[blockIdx.x];
  if (i == 0) base[NN] = NE;
}

// ---------------------------------------------------------------
// Scatter edges into CSR slots: esl[slot] = { src | t<<16, bits(decay) }.
// ---------------------------------------------------------------
__global__ __launch_bounds__(256)
void scatter_kernel(const int* __restrict__ ei, const float* __restrict__ ev,
                    const float* __restrict__ m1, const float* __restrict__ m2,
                    const int* __restrict__ base, int* __restrict__ fill,
                    int2* __restrict__ esl)
{
  int e = blockIdx.x * 256 + threadIdx.x;
  int src = ei[e];
  int dst = ei[NE + e];
  int t = (m1[e] > 0.5f) ? 1 : ((m2[e] > 0.5f) ? 2 : 0);
  float av = fabsf(ev[e]);
  float decay = exp2f(-0.15200309344504995f * av);      // 0.9^|v|
  int slot = base[dst] + atomicAdd(&fill[dst], 1);
  int2 v; v.x = src | (t << 16); v.y = __float_as_int(decay);
  esl[slot] = v;
}

// ---------------------------------------------------------------
// Fused per-node attention, wave-synchronous (no LDS, no barriers).
// One 64-lane wave per node; 4 nodes per 256-thread block.
// Softmax without max-shift (scores bounded ~11; fp32-safe; the global
// max-shift cancels exactly except a ~1e-10 denominator perturbation).
// Phase A: 16 edges x 4 heads (lane = e*4+h) -> a = exp(score).
// Phase B: 2 edges x 32 lanes, 4 comps/lane V accumulation; shfl exchange.
// NOTE: all __shfl ops sit in wave-uniform control flow (full EXEC) —
// a shfl inside the aw>0 branch reads undefined data from masked lanes.
// ---------------------------------------------------------------
__global__ __launch_bounds__(256)
void agg_kernel(const float* __restrict__ x,
                const unsigned short* __restrict__ Q,
                const unsigned short* __restrict__ K,
                const unsigned short* __restrict__ V,
                const int2* __restrict__ esl, const int* __restrict__ base,
                float* __restrict__ out)
{
  const int l = threadIdx.x & 63;
  const int n = blockIdx.x * 4 + (threadIdx.x >> 6);
  const int b0 = base[n], b1 = base[n + 1];
  const int eA = l >> 2, h = l & 3;       // phase-A role
  const int half = l >> 5, l31 = l & 31;  // phase-B role
  const int hB = l31 >> 3;                // head of this lane's 4 comps
  float acc0 = 0.f, acc1 = 0.f, acc2 = 0.f, acc3 = 0.f;
  float den = 0.f;                        // per-lane: denom for head (l&3)

  for (int cs = b0; cs < b1; cs += 16) {
    const int j = cs + eA;
    float a = 0.f;
    int ecx = 0;
    if (j < b1) {
      int2 ec = esl[j];
      ecx = ec.x;
      int src = ecx & 0xFFFF, t = ecx >> 16;
      const unsigned short* kr = K + ((size_t)t * NN + src) * DD + h * 32;
      const unsigned short* qr = Q + ((size_t)t * NN + n) * DD + h * 32;  // L1-hot
      float dot = 0.f;
#pragma unroll
      for (int i = 0; i < 4; ++i) {
        uint4 a4 = ((const uint4*)kr)[i];
        uint4 q4 = ((const uint4*)qr)[i];
        dot += pdot(a4.x, q4.x) + pdot(a4.y, q4.y) + pdot(a4.z, q4.z) + pdot(a4.w, q4.w);
      }
      a = __expf(dot * 0.17677669529663687f * __int_as_float(ec.y));
    }
    // denominator: butterfly over the 16 lanes sharing h = l&3 (full EXEC)
    float d = a;
    d += __shfl_xor(d, 4);
    d += __shfl_xor(d, 8);
    d += __shfl_xor(d, 16);
    d += __shfl_xor(d, 32);
    den += d;
    // phase B: V accumulation, 2 edges at a time; shfl BEFORE the branch
#pragma unroll
    for (int i = 0; i < 8; ++i) {
      int e2 = half + i * 2;
      float aw = __shfl(a, e2 * 4 + hB);    // uniform exec
      int   cd = __shfl(ecx, e2 * 4);       // uniform exec
      if (aw > 0.f) {
        int src = cd & 0xFFFF, t = cd >> 16;
        uint2 v2 = *(const uint2*)(V + ((size_t)t * NN + src) * DD + l31 * 4);
        acc0 += aw * __uint_as_float(v2.x << 16);
        acc1 += aw * __uint_as_float(v2.x & 0xFFFF0000u);
        acc2 += aw * __uint_as_float(v2.y << 16);
        acc3 += aw * __uint_as_float(v2.y & 0xFFFF0000u);
      }
    }
  }

  // combine the two half-wave partials (full EXEC)
  acc0 += __shfl_xor(acc0, 32);
  acc1 += __shfl_xor(acc1, 32);
  acc2 += __shfl_xor(acc2, 32);
  acc3 += __shfl_xor(acc3, 32);
  float dh = __shfl(den, hB) + 1e-16f;
  if (half == 0) {
    float4 xr = *(const float4*)(x + (size_t)n * DD + l31 * 4);
    float z0 = acc0 / dh, z1 = acc1 / dh, z2 = acc2 / dh, z3 = acc3 / dh;
    float4 o;
    o.x = xr.x + 0.5f * z0 * (1.0f + erff(z0 * 0.70710678118654752f));
    o.y = xr.y + 0.5f * z1 * (1.0f + erff(z1 * 0.70710678118654752f));
    o.z = xr.z + 0.5f * z2 * (1.0f + erff(z2 * 0.70710678118654752f));
    o.w = xr.w + 0.5f * z3 * (1.0f + erff(z3 * 0.70710678118654752f));
    *(float4*)(out + (size_t)n * DD + l31 * 4) = o;
  }
}

// ---------------------------------------------------------------
extern "C" void kernel_launch(void* const* d_in, const int* in_sizes, int n_in,
                              void* d_out, int out_size, void* d_ws, size_t ws_size,
                              hipStream_t stream)
{
  const float* x     = (const float*)d_in[0];
  const int*   ei    = (const int*)d_in[1];
  const float* ev    = (const float*)d_in[2];
  const float* m1    = (const float*)d_in[5];  // diff_time_same_var -> t=1
  const float* m2    = (const float*)d_in[6];  // diff_time_diff_var -> t=2
  const float* gamma = (const float*)d_in[8];
  const float* beta  = (const float*)d_in[9];
  const float* Wq    = (const float*)d_in[10];
  const float* bq    = (const float*)d_in[11];
  const float* Wk    = (const float*)d_in[12];
  const float* bk    = (const float*)d_in[13];
  const float* Wv    = (const float*)d_in[14];
  const float* bv    = (const float*)d_in[15];
  float* out = (float*)d_out;

  // ---- workspace layout ----
  unsigned short* Q  = (unsigned short*)d_ws;        // 3*NN*128 bf16
  unsigned short* Kb = Q  + (size_t)3 * NN * DD;
  unsigned short* Vb = Kb + (size_t)3 * NN * DD;
  unsigned short* Xn = Vb + (size_t)3 * NN * DD;     // NN*128 bf16
  unsigned short* Wt = Xn + (size_t)NN * DD;         // 9*16384 bf16
  int2*  esl  = (int2*)(Wt + 9 * 16384);             // NE int2 (8B-aligned)
  int*   deg  = (int*)(esl + NE);                    // NN
  int*   fill = deg + NN;                            // NN
  int*   base = fill + NN;                           // NN+1
  int*   bsum = base + NN + 1;                       // 157
  int*   boff = bsum + 157;                          // 157

  hipMemsetAsync(deg, 0, (size_t)2 * NN * sizeof(int), stream);  // deg + fill

  wt_kernel<<<9, 256, 0, stream>>>(Wq, Wk, Wv, Wt);
  ln_kernel<<<NN / 4, 256, 0, stream>>>(x, gamma, beta, Xn);
  qkv_kernel<<<dim3(9, NN / 64), 256, 0, stream>>>(Xn, bq, bk, bv, Wt, Q, Kb, Vb);
  hist_kernel<<<NE / 256, 256, 0, stream>>>(ei, deg);
  scan_part<<<157, 256, 0, stream>>>(deg, base, bsum);
  scan_mid<<<1, 64, 0, stream>>>(bsum, boff, 157);
  scan_add<<<157, 256, 0, stream>>>(base, boff);
  scatter_kernel<<<NE / 256, 256, 0, stream>>>(ei, ev, m1, m2, base, fill, esl);
  agg_kernel<<<NN / 4, 256, 0, stream>>>(x, Q, Kb, Vb, esl, base, out);
}

// Round 11
// 188.533 us; speedup vs baseline: 1.7306x; 1.1257x over previous
//
#include <hip/hip_runtime.h>
#include <math.h>

static constexpr int NN = 40000;   // nodes
static constexpr int NE = 640000;  // edges
static constexpr int DD = 128;     // feature dim
// H=4, DK=DE=32, P=1, n_layer=0

typedef __attribute__((ext_vector_type(8))) short short8;
typedef __attribute__((ext_vector_type(4))) float f32x4;

// ---------- helpers ----------
__device__ __forceinline__ unsigned short f2b(float f) {
  unsigned u = __float_as_uint(f);
  unsigned r = (u + 0x7FFFu + ((u >> 16) & 1u)) >> 16;  // RNE
  return (unsigned short)r;
}
// XOR swizzle for 256B-pitch LDS rows (row = byte>>8): flips 16B-chunk index
__device__ __forceinline__ int swz(int b) {
  return b ^ ((((b >> 8) & 7) << 4));
}
__device__ __forceinline__ float pdot(unsigned a, unsigned b) {
  float al = __uint_as_float(a << 16), ah = __uint_as_float(a & 0xFFFF0000u);
  float bl = __uint_as_float(b << 16), bh = __uint_as_float(b & 0xFFFF0000u);
  return al * bl + ah * bh;
}
__device__ __forceinline__ float blo(unsigned a) { return __uint_as_float(a << 16); }
__device__ __forceinline__ float bhi(unsigned a) { return __uint_as_float(a & 0xFFFF0000u); }

// ---------------------------------------------------------------
// Fused prologue: block-role split.
//   blocks [0,9):        weight transpose -> Wt[(mat*3+t)][c][d] bf16 (LDS-free)
//   blocks [9,5009):     LayerNorm x -> Xn bf16 (8 rows/block, float4/lane)
//   blocks [5009,7509):  edge histogram by dst
// ---------------------------------------------------------------
__global__ __launch_bounds__(256)
void prep_kernel(const float* __restrict__ Wq, const float* __restrict__ Wk,
                 const float* __restrict__ Wv, unsigned short* __restrict__ Wt,
                 const float* __restrict__ x, const float* __restrict__ gamma,
                 const float* __restrict__ beta, unsigned short* __restrict__ Xn,
                 const int* __restrict__ ei, int* __restrict__ deg)
{
  const int b = blockIdx.x;
  const int tid = threadIdx.x;
  if (b < 9) {
    const int mat = b / 3, t = b % 3;
    const float* W = (mat == 0) ? Wq : (mat == 1) ? Wk : Wv;
#pragma unroll
    for (int i = 0; i < 8; ++i) {
      int idx = i * 256 + tid;          // 0..2047
      int c = idx >> 4, ch = idx & 15;
      int h = c >> 5, k = c & 31;
      union { unsigned short s[8]; uint4 v; } u;
#pragma unroll
      for (int j = 0; j < 8; ++j) {
        int d = ch * 8 + j;
        u.s[j] = f2b(W[(size_t)((h * 3 + t) * 128 + d) * 32 + k]);
      }
      *(uint4*)&Wt[(size_t)b * 16384 + c * 128 + ch * 8] = u.v;
    }
  } else if (b < 5009) {
    const int r = (b - 9) * 8 + (tid >> 5);   // 8 rows/block, 32 lanes/row
    const int l32 = tid & 31;
    float4 v = *(const float4*)(x + (size_t)r * DD + l32 * 4);
    float s  = v.x + v.y + v.z + v.w;
    float ss = v.x * v.x + v.y * v.y + v.z * v.z + v.w * v.w;
#pragma unroll
    for (int off = 1; off < 32; off <<= 1) { s += __shfl_xor(s, off); ss += __shfl_xor(ss, off); }
    float mu = s * (1.f / 128.f);
    float rs = rsqrtf(ss * (1.f / 128.f) - mu * mu + 1e-5f);
    float4 g = *(const float4*)(gamma + l32 * 4);
    float4 bb = *(const float4*)(beta + l32 * 4);
    ushort4 o;
    o.x = f2b((v.x - mu) * rs * g.x + bb.x);
    o.y = f2b((v.y - mu) * rs * g.y + bb.y);
    o.z = f2b((v.z - mu) * rs * g.z + bb.z);
    o.w = f2b((v.w - mu) * rs * g.w + bb.w);
    *(ushort4*)(Xn + (size_t)r * DD + l32 * 4) = o;
  } else {
    int e = (b - 5009) * 256 + tid;
    atomicAdd(&deg[ei[NE + e]], 1);
  }
}

// ---------------------------------------------------------------
// QKV projection, bf16 MFMA. grid (9, 625), block 256 (4 waves).
// 64-row x 128-col tile per block; wave w owns rows w*16..+15.
// ---------------------------------------------------------------
__global__ __launch_bounds__(256)
void qkv_kernel(const unsigned short* __restrict__ Xn,
                const float* __restrict__ bq, const float* __restrict__ bk,
                const float* __restrict__ bv,
                const unsigned short* __restrict__ Wt,
                unsigned short* __restrict__ Qo, unsigned short* __restrict__ Ko,
                unsigned short* __restrict__ Vo)
{
  __shared__ unsigned char xs[16384];  // 64 rows x 256B (swizzled)
  __shared__ unsigned char wt[32768];  // 128 c-rows x 256B (swizzled)
  const int tid = threadIdx.x;
  const int lane = tid & 63;
  const int w = tid >> 6;
  const int l15 = lane & 15, kh = lane >> 4;
  const int combo = blockIdx.x;
  const int n0 = blockIdx.y * 64;
  const int mat = combo / 3, t = combo % 3;
  const float* B = (mat == 0) ? bq : (mat == 1) ? bk : bv;
  unsigned short* O = (mat == 0) ? Qo : (mat == 1) ? Ko : Vo;

  // ---- stage Wt slab (32KB) ----
#pragma unroll
  for (int i = 0; i < 8; ++i) {
    int idx = i * 256 + tid;
    int rr = idx >> 4, ch = idx & 15;
    uint4 d4 = *(const uint4*)(Wt + (size_t)combo * 16384 + rr * 128 + ch * 8);
    *(uint4*)(wt + swz(rr * 256 + ch * 16)) = d4;
  }
  // ---- stage Xn tile (16KB) ----
#pragma unroll
  for (int i = 0; i < 4; ++i) {
    int idx = i * 256 + tid;
    int rr = idx >> 4, ch = idx & 15;
    uint4 d4 = *(const uint4*)(Xn + (size_t)(n0 + rr) * DD + ch * 8);
    *(uint4*)(xs + swz(rr * 256 + ch * 16)) = d4;
  }

  // ---- init acc with bias ----
  f32x4 acc[8];
#pragma unroll
  for (int ct = 0; ct < 8; ++ct) {
    int cc = ct * 16 + l15;
    float bb = B[((cc >> 5) * 3 + t) * 32 + (cc & 31)];
    f32x4 bi = {bb, bb, bb, bb};
    acc[ct] = bi;
  }
  __syncthreads();

  // ---- MFMA: 4 k-steps x 8 col-tiles ----
#pragma unroll
  for (int ks = 0; ks < 4; ++ks) {
    short8 a0 = *(const short8*)(xs + swz((w * 16 + l15) * 256 + ks * 64 + kh * 16));
#pragma unroll
    for (int ct = 0; ct < 8; ++ct) {
      short8 bf = *(const short8*)(wt + swz((ct * 16 + l15) * 256 + ks * 64 + kh * 16));
      acc[ct] = __builtin_amdgcn_mfma_f32_16x16x32_bf16(a0, bf, acc[ct], 0, 0, 0);
    }
  }

  // ---- epilogue: repack own rows via LDS (wave-private region) ----
#pragma unroll
  for (int ct = 0; ct < 8; ++ct)
#pragma unroll
    for (int rg = 0; rg < 4; ++rg) {
      int rr = w * 16 + kh * 4 + rg;
      int cc = ct * 16 + l15;
      *(unsigned short*)(xs + swz(rr * 256 + cc * 2)) = f2b(acc[ct][rg]);
    }
  __syncthreads();
#pragma unroll
  for (int i = 0; i < 4; ++i) {
    int idx = i * 256 + tid;
    int rr = idx >> 4, ch = idx & 15;
    uint4 d4 = *(const uint4*)(xs + swz(rr * 256 + ch * 16));
    *(uint4*)(O + ((size_t)t * NN + n0 + rr) * DD + ch * 8) = d4;
  }
}

// ---- two-level scan: part + (mid+add fused) ----
__global__ __launch_bounds__(256)
void scan_part(const int* __restrict__ deg, int* __restrict__ base, int* __restrict__ bsum)
{
  const int b = blockIdx.x, tid = threadIdx.x;
  int i = b * 256 + tid;
  int v = (i < NN) ? deg[i] : 0;
  int xv = v;
#pragma unroll
  for (int off = 1; off < 64; off <<= 1) {
    int y = __shfl_up(xv, off);
    if ((tid & 63) >= off) xv += y;
  }
  __shared__ int wsum[4];
  if ((tid & 63) == 63) wsum[tid >> 6] = xv;
  __syncthreads();
  int add = 0;
  if (tid >= 64)  add += wsum[0];
  if (tid >= 128) add += wsum[1];
  if (tid >= 192) add += wsum[2];
  xv += add;
  if (i < NN) base[i] = xv - v;   // local exclusive
  if (tid == 255) bsum[b] = xv;
}

// Each block sums bsum[i < blockIdx.x] (157 values) and adds to its chunk.
__global__ __launch_bounds__(256)
void scan_fin(int* __restrict__ base, const int* __restrict__ bsum)
{
  const int b = blockIdx.x, tid = threadIdx.x;
  int v = (tid < b && tid < 157) ? bsum[tid] : 0;
#pragma unroll
  for (int off = 1; off < 64; off <<= 1) v += __shfl_xor(v, off);
  __shared__ int ws4[4];
  if ((tid & 63) == 0) ws4[tid >> 6] = v;
  __syncthreads();
  int boff = ws4[0] + ws4[1] + ws4[2] + ws4[3];
  int i = b * 256 + tid;
  if (i < NN) base[i] += boff;
  if (b == 0 && tid == 0) base[NN] = NE;
}

// ---------------------------------------------------------------
// Scatter edges into CSR slots: esl[slot] = { src | t<<16, bits(decay) }.
// ---------------------------------------------------------------
__global__ __launch_bounds__(256)
void scatter_kernel(const int* __restrict__ ei, const float* __restrict__ ev,
                    const float* __restrict__ m1, const float* __restrict__ m2,
                    const int* __restrict__ base, int* __restrict__ fill,
                    int2* __restrict__ esl)
{
  int e = blockIdx.x * 256 + threadIdx.x;
  int src = ei[e];
  int dst = ei[NE + e];
  int t = (m1[e] > 0.5f) ? 1 : ((m2[e] > 0.5f) ? 2 : 0);
  float av = fabsf(ev[e]);
  float decay = exp2f(-0.15200309344504995f * av);      // 0.9^|v|
  int slot = base[dst] + atomicAdd(&fill[dst], 1);
  int2 v; v.x = src | (t << 16); v.y = __float_as_int(decay);
  esl[slot] = v;
}

// ---------------------------------------------------------------
// Fused per-node attention, wave-synchronous (no LDS, no barriers).
// One 64-lane wave per node; 4 nodes per 256-thread block.
// Softmax without max-shift (scores bounded ~11; fp32-safe; the global
// max-shift cancels except a ~1e-10 denominator perturbation).
// Phase A: 16 edges x 4 heads (lane = e*4+h) -> a = exp(score).
// Phase B: 4 edges x 16 lanes, uint4 V loads, 8 comps/lane.
// All __shfl ops in wave-uniform control flow (full EXEC).
// ---------------------------------------------------------------
__global__ __launch_bounds__(256)
void agg_kernel(const float* __restrict__ x,
                const unsigned short* __restrict__ Q,
                const unsigned short* __restrict__ K,
                const unsigned short* __restrict__ V,
                const int2* __restrict__ esl, const int* __restrict__ base,
                float* __restrict__ out)
{
  const int l = threadIdx.x & 63;
  const int n = blockIdx.x * 4 + (threadIdx.x >> 6);
  const int b0 = base[n], b1 = base[n + 1];
  const int eA = l >> 2, h = l & 3;        // phase-A role
  const int g16 = l >> 4, l15 = l & 15;    // phase-B role: group, lane-in-group
  const int hB = l15 >> 2;                 // head of this lane's 8 comps
  float acc[8] = {0.f, 0.f, 0.f, 0.f, 0.f, 0.f, 0.f, 0.f};
  float den = 0.f;                         // per-lane: denom for head (l&3)

  for (int cs = b0; cs < b1; cs += 16) {
    const int j = cs + eA;
    float a = 0.f;
    int ecx = 0;
    if (j < b1) {
      int2 ec = esl[j];
      ecx = ec.x;
      int src = ecx & 0xFFFF, t = ecx >> 16;
      const unsigned short* kr = K + ((size_t)t * NN + src) * DD + h * 32;
      const unsigned short* qr = Q + ((size_t)t * NN + n) * DD + h * 32;  // L1-hot
      float dot = 0.f;
#pragma unroll
      for (int i = 0; i < 4; ++i) {
        uint4 a4 = ((const uint4*)kr)[i];
        uint4 q4 = ((const uint4*)qr)[i];
        dot += pdot(a4.x, q4.x) + pdot(a4.y, q4.y) + pdot(a4.z, q4.z) + pdot(a4.w, q4.w);
      }
      a = __expf(dot * 0.17677669529663687f * __int_as_float(ec.y));
    }
    // denominator: butterfly over the 16 lanes sharing h = l&3 (full EXEC)
    float d = a;
    d += __shfl_xor(d, 4);
    d += __shfl_xor(d, 8);
    d += __shfl_xor(d, 16);
    d += __shfl_xor(d, 32);
    den += d;
    // phase B: 4 edges at a time, 16 lanes/edge; shfl BEFORE the branch
#pragma unroll
    for (int i = 0; i < 4; ++i) {
      int e2 = g16 + i * 4;
      float aw = __shfl(a, e2 * 4 + hB);    // uniform exec
      int   cd = __shfl(ecx, e2 * 4);       // uniform exec
      if (aw > 0.f) {
        int src = cd & 0xFFFF, t = cd >> 16;
        uint4 v4 = *(const uint4*)(V + ((size_t)t * NN + src) * DD + l15 * 8);
        acc[0] += aw * blo(v4.x); acc[1] += aw * bhi(v4.x);
        acc[2] += aw * blo(v4.y); acc[3] += aw * bhi(v4.y);
        acc[4] += aw * blo(v4.z); acc[5] += aw * bhi(v4.z);
        acc[6] += aw * blo(v4.w); acc[7] += aw * bhi(v4.w);
      }
    }
  }

  // combine the four 16-lane-group partials (full EXEC)
#pragma unroll
  for (int k2 = 0; k2 < 8; ++k2) {
    acc[k2] += __shfl_xor(acc[k2], 16);
    acc[k2] += __shfl_xor(acc[k2], 32);
  }
  float dh = __shfl(den, hB) + 1e-16f;     // lane hB holds den for head hB
  if (g16 == 0) {
    const float* xr = x + (size_t)n * DD + l15 * 8;
    float4 x0 = *(const float4*)xr;
    float4 x1 = *(const float4*)(xr + 4);
    float z[8];
#pragma unroll
    for (int k2 = 0; k2 < 8; ++k2) {
      float zz = acc[k2] / dh;
      z[k2] = 0.5f * zz * (1.0f + erff(zz * 0.70710678118654752f));
    }
    float4 o0 = make_float4(x0.x + z[0], x0.y + z[1], x0.z + z[2], x0.w + z[3]);
    float4 o1 = make_float4(x1.x + z[4], x1.y + z[5], x1.z + z[6], x1.w + z[7]);
    float* po = out + (size_t)n * DD + l15 * 8;
    *(float4*)po = o0;
    *(float4*)(po + 4) = o1;
  }
}

// ---------------------------------------------------------------
extern "C" void kernel_launch(void* const* d_in, const int* in_sizes, int n_in,
                              void* d_out, int out_size, void* d_ws, size_t ws_size,
                              hipStream_t stream)
{
  const float* x     = (const float*)d_in[0];
  const int*   ei    = (const int*)d_in[1];
  const float* ev    = (const float*)d_in[2];
  const float* m1    = (const float*)d_in[5];  // diff_time_same_var -> t=1
  const float* m2    = (const float*)d_in[6];  // diff_time_diff_var -> t=2
  const float* gamma = (const float*)d_in[8];
  const float* beta  = (const float*)d_in[9];
  const float* Wq    = (const float*)d_in[10];
  const float* bq    = (const float*)d_in[11];
  const float* Wk    = (const float*)d_in[12];
  const float* bk    = (const float*)d_in[13];
  const float* Wv    = (const float*)d_in[14];
  const float* bv    = (const float*)d_in[15];
  float* out = (float*)d_out;

  // ---- workspace layout ----
  unsigned short* Q  = (unsigned short*)d_ws;        // 3*NN*128 bf16
  unsigned short* Kb = Q  + (size_t)3 * NN * DD;
  unsigned short* Vb = Kb + (size_t)3 * NN * DD;
  unsigned short* Xn = Vb + (size_t)3 * NN * DD;     // NN*128 bf16
  unsigned short* Wt = Xn + (size_t)NN * DD;         // 9*16384 bf16
  int2*  esl  = (int2*)(Wt + 9 * 16384);             // NE int2 (8B-aligned)
  int*   deg  = (int*)(esl + NE);                    // NN
  int*   fill = deg + NN;                            // NN
  int*   base = fill + NN;                           // NN+1
  int*   bsum = base + NN + 1;                       // 157

  hipMemsetAsync(deg, 0, (size_t)2 * NN * sizeof(int), stream);  // deg + fill

  prep_kernel<<<7509, 256, 0, stream>>>(Wq, Wk, Wv, Wt, x, gamma, beta, Xn, ei, deg);
  qkv_kernel<<<dim3(9, NN / 64), 256, 0, stream>>>(Xn, bq, bk, bv, Wt, Q, Kb, Vb);
  scan_part<<<157, 256, 0, stream>>>(deg, base, bsum);
  scan_fin<<<157, 256, 0, stream>>>(base, bsum);
  scatter_kernel<<<NE / 256, 256, 0, stream>>>(ei, ev, m1, m2, base, fill, esl);
  agg_kernel<<<NN / 4, 256, 0, stream>>>(x, Q, Kb, Vb, esl, base, out);
}

// Round 12
// 153.429 us; speedup vs baseline: 2.1266x; 1.2288x over previous
//
#include <hip/hip_runtime.h>
#include <math.h>

static constexpr int NN = 40000;   // nodes
static constexpr int NE = 640000;  // edges
static constexpr int DD = 128;     // feature dim
// H=4, DK=DE=32, P=1, n_layer=0

typedef __attribute__((ext_vector_type(8))) short short8;
typedef __attribute__((ext_vector_type(4))) float f32x4;

// ---------- helpers ----------
__device__ __forceinline__ unsigned short f2b(float f) {
  unsigned u = __float_as_uint(f);
  unsigned r = (u + 0x7FFFu + ((u >> 16) & 1u)) >> 16;  // RNE
  return (unsigned short)r;
}
// XOR swizzle for 256B-pitch LDS rows (row = byte>>8): flips 16B-chunk index
__device__ __forceinline__ int swz(int b) {
  return b ^ ((((b >> 8) & 7) << 4));
}
__device__ __forceinline__ float pdot(unsigned a, unsigned b) {
  float al = __uint_as_float(a << 16), ah = __uint_as_float(a & 0xFFFF0000u);
  float bl = __uint_as_float(b << 16), bh = __uint_as_float(b & 0xFFFF0000u);
  return al * bl + ah * bh;
}
__device__ __forceinline__ float blo(unsigned a) { return __uint_as_float(a << 16); }
__device__ __forceinline__ float bhi(unsigned a) { return __uint_as_float(a & 0xFFFF0000u); }

// ---------------------------------------------------------------
// Fused prologue: block-role split.
//   blocks [0,9):        weight transpose -> Wt[(mat*3+t)][c][d] bf16 (LDS-free)
//   blocks [9,5009):     LayerNorm x -> Xn bf16 (8 rows/block, float4/lane)
//   blocks [5009,7509):  edge histogram by dst + per-edge rank record
// ---------------------------------------------------------------
__global__ __launch_bounds__(256)
void prep_kernel(const float* __restrict__ Wq, const float* __restrict__ Wk,
                 const float* __restrict__ Wv, unsigned short* __restrict__ Wt,
                 const float* __restrict__ x, const float* __restrict__ gamma,
                 const float* __restrict__ beta, unsigned short* __restrict__ Xn,
                 const int* __restrict__ ei, int* __restrict__ deg,
                 int* __restrict__ rank)
{
  const int b = blockIdx.x;
  const int tid = threadIdx.x;
  if (b < 9) {
    const int mat = b / 3, t = b % 3;
    const float* W = (mat == 0) ? Wq : (mat == 1) ? Wk : Wv;
#pragma unroll
    for (int i = 0; i < 8; ++i) {
      int idx = i * 256 + tid;          // 0..2047
      int c = idx >> 4, ch = idx & 15;
      int h = c >> 5, k = c & 31;
      union { unsigned short s[8]; uint4 v; } u;
#pragma unroll
      for (int j = 0; j < 8; ++j) {
        int d = ch * 8 + j;
        u.s[j] = f2b(W[(size_t)((h * 3 + t) * 128 + d) * 32 + k]);
      }
      *(uint4*)&Wt[(size_t)b * 16384 + c * 128 + ch * 8] = u.v;
    }
  } else if (b < 5009) {
    const int r = (b - 9) * 8 + (tid >> 5);   // 8 rows/block, 32 lanes/row
    const int l32 = tid & 31;
    float4 v = *(const float4*)(x + (size_t)r * DD + l32 * 4);
    float s  = v.x + v.y + v.z + v.w;
    float ss = v.x * v.x + v.y * v.y + v.z * v.z + v.w * v.w;
#pragma unroll
    for (int off = 1; off < 32; off <<= 1) { s += __shfl_xor(s, off); ss += __shfl_xor(ss, off); }
    float mu = s * (1.f / 128.f);
    float rs = rsqrtf(ss * (1.f / 128.f) - mu * mu + 1e-5f);
    float4 g = *(const float4*)(gamma + l32 * 4);
    float4 bb = *(const float4*)(beta + l32 * 4);
    ushort4 o;
    o.x = f2b((v.x - mu) * rs * g.x + bb.x);
    o.y = f2b((v.y - mu) * rs * g.y + bb.y);
    o.z = f2b((v.z - mu) * rs * g.z + bb.z);
    o.w = f2b((v.w - mu) * rs * g.w + bb.w);
    *(ushort4*)(Xn + (size_t)r * DD + l32 * 4) = o;
  } else {
    int e = (b - 5009) * 256 + tid;
    rank[e] = atomicAdd(&deg[ei[NE + e]], 1);
  }
}

// ---------------------------------------------------------------
// QKV projection, bf16 MFMA. grid (9, 625), block 256 (4 waves).
// 64-row x 128-col tile per block; wave w owns rows w*16..+15.
// Q -> Qo [t*NN+n][128]; K/V -> KVo interleaved [t*NN+n][256] (K:0-127, V:128-255).
// ---------------------------------------------------------------
__global__ __launch_bounds__(256)
void qkv_kernel(const unsigned short* __restrict__ Xn,
                const float* __restrict__ bq, const float* __restrict__ bk,
                const float* __restrict__ bv,
                const unsigned short* __restrict__ Wt,
                unsigned short* __restrict__ Qo, unsigned short* __restrict__ KVo)
{
  __shared__ unsigned char xs[16384];  // 64 rows x 256B (swizzled)
  __shared__ unsigned char wt[32768];  // 128 c-rows x 256B (swizzled)
  const int tid = threadIdx.x;
  const int lane = tid & 63;
  const int w = tid >> 6;
  const int l15 = lane & 15, kh = lane >> 4;
  const int combo = blockIdx.x;
  const int n0 = blockIdx.y * 64;
  const int mat = combo / 3, t = combo % 3;
  const float* B = (mat == 0) ? bq : (mat == 1) ? bk : bv;
  unsigned short* O; int ostride;
  if (mat == 0)      { O = Qo;        ostride = 128; }
  else if (mat == 1) { O = KVo;       ostride = 256; }
  else               { O = KVo + 128; ostride = 256; }

  // ---- stage Wt slab (32KB) ----
#pragma unroll
  for (int i = 0; i < 8; ++i) {
    int idx = i * 256 + tid;
    int rr = idx >> 4, ch = idx & 15;
    uint4 d4 = *(const uint4*)(Wt + (size_t)combo * 16384 + rr * 128 + ch * 8);
    *(uint4*)(wt + swz(rr * 256 + ch * 16)) = d4;
  }
  // ---- stage Xn tile (16KB) ----
#pragma unroll
  for (int i = 0; i < 4; ++i) {
    int idx = i * 256 + tid;
    int rr = idx >> 4, ch = idx & 15;
    uint4 d4 = *(const uint4*)(Xn + (size_t)(n0 + rr) * DD + ch * 8);
    *(uint4*)(xs + swz(rr * 256 + ch * 16)) = d4;
  }

  // ---- init acc with bias ----
  f32x4 acc[8];
#pragma unroll
  for (int ct = 0; ct < 8; ++ct) {
    int cc = ct * 16 + l15;
    float bb = B[((cc >> 5) * 3 + t) * 32 + (cc & 31)];
    f32x4 bi = {bb, bb, bb, bb};
    acc[ct] = bi;
  }
  __syncthreads();

  // ---- MFMA: 4 k-steps x 8 col-tiles ----
#pragma unroll
  for (int ks = 0; ks < 4; ++ks) {
    short8 a0 = *(const short8*)(xs + swz((w * 16 + l15) * 256 + ks * 64 + kh * 16));
#pragma unroll
    for (int ct = 0; ct < 8; ++ct) {
      short8 bf = *(const short8*)(wt + swz((ct * 16 + l15) * 256 + ks * 64 + kh * 16));
      acc[ct] = __builtin_amdgcn_mfma_f32_16x16x32_bf16(a0, bf, acc[ct], 0, 0, 0);
    }
  }

  // ---- epilogue: repack own rows via LDS (wave-private region) ----
#pragma unroll
  for (int ct = 0; ct < 8; ++ct)
#pragma unroll
    for (int rg = 0; rg < 4; ++rg) {
      int rr = w * 16 + kh * 4 + rg;
      int cc = ct * 16 + l15;
      *(unsigned short*)(xs + swz(rr * 256 + cc * 2)) = f2b(acc[ct][rg]);
    }
  __syncthreads();
#pragma unroll
  for (int i = 0; i < 4; ++i) {
    int idx = i * 256 + tid;
    int rr = idx >> 4, ch = idx & 15;
    uint4 d4 = *(const uint4*)(xs + swz(rr * 256 + ch * 16));
    *(uint4*)(O + ((size_t)t * NN + n0 + rr) * ostride + ch * 8) = d4;
  }
}

// ---- two-level scan: part + (mid+add fused) ----
__global__ __launch_bounds__(256)
void scan_part(const int* __restrict__ deg, int* __restrict__ base, int* __restrict__ bsum)
{
  const int b = blockIdx.x, tid = threadIdx.x;
  int i = b * 256 + tid;
  int v = (i < NN) ? deg[i] : 0;
  int xv = v;
#pragma unroll
  for (int off = 1; off < 64; off <<= 1) {
    int y = __shfl_up(xv, off);
    if ((tid & 63) >= off) xv += y;
  }
  __shared__ int wsum[4];
  if ((tid & 63) == 63) wsum[tid >> 6] = xv;
  __syncthreads();
  int add = 0;
  if (tid >= 64)  add += wsum[0];
  if (tid >= 128) add += wsum[1];
  if (tid >= 192) add += wsum[2];
  xv += add;
  if (i < NN) base[i] = xv - v;   // local exclusive
  if (tid == 255) bsum[b] = xv;
}

// Each block sums bsum[i < blockIdx.x] (157 values) and adds to its chunk.
__global__ __launch_bounds__(256)
void scan_fin(int* __restrict__ base, const int* __restrict__ bsum)
{
  const int b = blockIdx.x, tid = threadIdx.x;
  int v = (tid < b && tid < 157) ? bsum[tid] : 0;
#pragma unroll
  for (int off = 1; off < 64; off <<= 1) v += __shfl_xor(v, off);
  __shared__ int ws4[4];
  if ((tid & 63) == 0) ws4[tid >> 6] = v;
  __syncthreads();
  int boff = ws4[0] + ws4[1] + ws4[2] + ws4[3];
  int i = b * 256 + tid;
  if (i < NN) base[i] += boff;
  if (b == 0 && tid == 0) base[NN] = NE;
}

// ---------------------------------------------------------------
// Scatter edges into CSR slots (no atomics: slot = base[dst] + rank[e]).
// esl[slot] = { src | t<<16, bits(decay) }.
// ---------------------------------------------------------------
__global__ __launch_bounds__(256)
void scatter_kernel(const int* __restrict__ ei, const float* __restrict__ ev,
                    const float* __restrict__ m1, const float* __restrict__ m2,
                    const int* __restrict__ base, const int* __restrict__ rank,
                    int2* __restrict__ esl)
{
  int e = blockIdx.x * 256 + threadIdx.x;
  int src = ei[e];
  int dst = ei[NE + e];
  int t = (m1[e] > 0.5f) ? 1 : ((m2[e] > 0.5f) ? 2 : 0);
  float av = fabsf(ev[e]);
  float decay = exp2f(-0.15200309344504995f * av);      // 0.9^|v|
  int slot = base[dst] + rank[e];
  int2 v; v.x = src | (t << 16); v.y = __float_as_int(decay);
  esl[slot] = v;
}

// ---------------------------------------------------------------
// Fused per-node attention, wave-synchronous, BRANCHLESS phases.
// One 64-lane wave per node; 4 nodes per 256-thread block.
// Padding lanes clamp to the node's last edge (valid address) and carry
// weight 0 — identical numerics, but no exec-masked loads, so all gathers
// in a chunk issue concurrently (4x memory-level parallelism in phase B).
// Phase A: 16 edges x 4 heads (lane = e*4+h) -> a = exp(score).
// Phase B: 4 edges x 16 lanes, uint4 V loads from KV row second half.
// ---------------------------------------------------------------
__global__ __launch_bounds__(256)
void agg_kernel(const float* __restrict__ x,
                const unsigned short* __restrict__ Q,
                const unsigned short* __restrict__ KV,
                const int2* __restrict__ esl, const int* __restrict__ base,
                float* __restrict__ out)
{
  const int l = threadIdx.x & 63;
  const int n = blockIdx.x * 4 + (threadIdx.x >> 6);
  const int b0 = base[n], b1 = base[n + 1];
  const int eA = l >> 2, h = l & 3;        // phase-A role
  const int g16 = l >> 4, l15 = l & 15;    // phase-B role: group, lane-in-group
  const int hB = l15 >> 2;                 // head of this lane's 8 comps
  float acc[8] = {0.f, 0.f, 0.f, 0.f, 0.f, 0.f, 0.f, 0.f};
  float den = 0.f;                         // per-lane: denom for head (l&3)

  for (int cs = b0; cs < b1; cs += 16) {
    const int j = cs + eA;
    const bool act = (j < b1);
    const int jc = act ? j : (b1 - 1);     // clamp: always a valid slot
    int2 ec = esl[jc];
    const int ecx = ec.x;
    {
      int src = ecx & 0xFFFF, t = ecx >> 16;
      const unsigned short* kr = KV + ((size_t)t * NN + src) * 256 + h * 32;
      const unsigned short* qr = Q + ((size_t)t * NN + n) * DD + h * 32;  // L1-hot
      float dot = 0.f;
#pragma unroll
      for (int i = 0; i < 4; ++i) {
        uint4 a4 = ((const uint4*)kr)[i];
        uint4 q4 = ((const uint4*)qr)[i];
        dot += pdot(a4.x, q4.x) + pdot(a4.y, q4.y) + pdot(a4.z, q4.z) + pdot(a4.w, q4.w);
      }
      float e0 = __expf(dot * 0.17677669529663687f * __int_as_float(ec.y));
      den += act ? e0 : 0.f;   // placeholder; real reduce below uses 'a'
      den -= act ? e0 : 0.f;
      ec.y = __float_as_int(act ? e0 : 0.f);
    }
    const float a = __int_as_float(ec.y);
    // denominator: butterfly over the 16 lanes sharing h = l&3 (full EXEC)
    float d = a;
    d += __shfl_xor(d, 4);
    d += __shfl_xor(d, 8);
    d += __shfl_xor(d, 16);
    d += __shfl_xor(d, 32);
    den += d;
    // phase B: 4 edges at a time, 16 lanes/edge; branchless V gather+FMA
#pragma unroll
    for (int i = 0; i < 4; ++i) {
      int e2 = g16 + i * 4;
      float aw = __shfl(a, e2 * 4 + hB);    // uniform exec
      int   cd = __shfl(ecx, e2 * 4);       // uniform exec
      int src = cd & 0xFFFF, t = cd >> 16;
      uint4 v4 = *(const uint4*)(KV + ((size_t)t * NN + src) * 256 + 128 + l15 * 8);
      acc[0] += aw * blo(v4.x); acc[1] += aw * bhi(v4.x);
      acc[2] += aw * blo(v4.y); acc[3] += aw * bhi(v4.y);
      acc[4] += aw * blo(v4.z); acc[5] += aw * bhi(v4.z);
      acc[6] += aw * blo(v4.w); acc[7] += aw * bhi(v4.w);
    }
  }

  // combine the four 16-lane-group partials (full EXEC)
#pragma unroll
  for (int k2 = 0; k2 < 8; ++k2) {
    acc[k2] += __shfl_xor(acc[k2], 16);
    acc[k2] += __shfl_xor(acc[k2], 32);
  }
  float dh = __shfl(den, hB) + 1e-16f;     // lane hB holds den for head hB
  if (g16 == 0) {
    const float* xr = x + (size_t)n * DD + l15 * 8;
    float4 x0 = *(const float4*)xr;
    float4 x1 = *(const float4*)(xr + 4);
    float z[8];
#pragma unroll
    for (int k2 = 0; k2 < 8; ++k2) {
      float zz = acc[k2] / dh;
      z[k2] = 0.5f * zz * (1.0f + erff(zz * 0.70710678118654752f));
    }
    float4 o0 = make_float4(x0.x + z[0], x0.y + z[1], x0.z + z[2], x0.w + z[3]);
    float4 o1 = make_float4(x1.x + z[4], x1.y + z[5], x1.z + z[6], x1.w + z[7]);
    float* po = out + (size_t)n * DD + l15 * 8;
    *(float4*)po = o0;
    *(float4*)(po + 4) = o1;
  }
}

// ---------------------------------------------------------------
extern "C" void kernel_launch(void* const* d_in, const int* in_sizes, int n_in,
                              void* d_out, int out_size, void* d_ws, size_t ws_size,
                              hipStream_t stream)
{
  const float* x     = (const float*)d_in[0];
  const int*   ei    = (const int*)d_in[1];
  const float* ev    = (const float*)d_in[2];
  const float* m1    = (const float*)d_in[5];  // diff_time_same_var -> t=1
  const float* m2    = (const float*)d_in[6];  // diff_time_diff_var -> t=2
  const float* gamma = (const float*)d_in[8];
  const float* beta  = (const float*)d_in[9];
  const float* Wq    = (const float*)d_in[10];
  const float* bq    = (const float*)d_in[11];
  const float* Wk    = (const float*)d_in[12];
  const float* bk    = (const float*)d_in[13];
  const float* Wv    = (const float*)d_in[14];
  const float* bv    = (const float*)d_in[15];
  float* out = (float*)d_out;

  // ---- workspace layout ----
  unsigned short* Q  = (unsigned short*)d_ws;        // 3*NN*128 bf16
  unsigned short* KV = Q  + (size_t)3 * NN * DD;     // 3*NN*256 bf16 (K|V interleaved)
  unsigned short* Xn = KV + (size_t)3 * NN * 256;    // NN*128 bf16
  unsigned short* Wt = Xn + (size_t)NN * DD;         // 9*16384 bf16
  int2*  esl  = (int2*)(Wt + 9 * 16384);             // NE int2 (8B-aligned)
  int*   rank = (int*)(esl + NE);                    // NE
  int*   deg  = rank + NE;                           // NN
  int*   base = deg + NN;                            // NN+1
  int*   bsum = base + NN + 1;                       // 157

  hipMemsetAsync(deg, 0, (size_t)NN * sizeof(int), stream);  // deg only

  prep_kernel<<<7509, 256, 0, stream>>>(Wq, Wk, Wv, Wt, x, gamma, beta, Xn, ei, deg, rank);
  qkv_kernel<<<dim3(9, NN / 64), 256, 0, stream>>>(Xn, bq, bk, bv, Wt, Q, KV);
  scan_part<<<157, 256, 0, stream>>>(deg, base, bsum);
  scan_fin<<<157, 256, 0, stream>>>(base, bsum);
  scatter_kernel<<<NE / 256, 256, 0, stream>>>(ei, ev, m1, m2, base, rank, esl);
  agg_kernel<<<NN / 4, 256, 0, stream>>>(x, Q, KV, esl, base, out);
}

// Round 13
// 148.423 us; speedup vs baseline: 2.1983x; 1.0337x over previous
//
#include <hip/hip_runtime.h>
#include <math.h>

static constexpr int NN = 40000;   // nodes
static constexpr int NE = 640000;  // edges
static constexpr int DD = 128;     // feature dim
// H=4, DK=DE=32, P=1, n_layer=0

typedef __attribute__((ext_vector_type(8))) short short8;
typedef __attribute__((ext_vector_type(4))) float f32x4;

// ---------- helpers ----------
__device__ __forceinline__ unsigned short f2b(float f) {
  unsigned u = __float_as_uint(f);
  unsigned r = (u + 0x7FFFu + ((u >> 16) & 1u)) >> 16;  // RNE
  return (unsigned short)r;
}
// XOR swizzle for 256B-pitch LDS rows (row = byte>>8): flips 16B-chunk index
__device__ __forceinline__ int swz(int b) {
  return b ^ ((((b >> 8) & 7) << 4));
}
__device__ __forceinline__ float pdot(unsigned a, unsigned b) {
  float al = __uint_as_float(a << 16), ah = __uint_as_float(a & 0xFFFF0000u);
  float bl = __uint_as_float(b << 16), bh = __uint_as_float(b & 0xFFFF0000u);
  return al * bl + ah * bh;
}
__device__ __forceinline__ float blo(unsigned a) { return __uint_as_float(a << 16); }
__device__ __forceinline__ float bhi(unsigned a) { return __uint_as_float(a & 0xFFFF0000u); }

// ---------------------------------------------------------------
// Fused prologue: block-role split.
//   blocks [0,9):        weight transpose -> Wt[(mat*3+t)][c][d] bf16 (LDS-free)
//   blocks [9,5009):     LayerNorm x -> Xn bf16 (8 rows/block, float4/lane)
//   blocks [5009,7509):  edge histogram by dst + per-edge rank record
// ---------------------------------------------------------------
__global__ __launch_bounds__(256)
void prep_kernel(const float* __restrict__ Wq, const float* __restrict__ Wk,
                 const float* __restrict__ Wv, unsigned short* __restrict__ Wt,
                 const float* __restrict__ x, const float* __restrict__ gamma,
                 const float* __restrict__ beta, unsigned short* __restrict__ Xn,
                 const int* __restrict__ ei, int* __restrict__ deg,
                 int* __restrict__ rank)
{
  const int b = blockIdx.x;
  const int tid = threadIdx.x;
  if (b < 9) {
    const int mat = b / 3, t = b % 3;
    const float* W = (mat == 0) ? Wq : (mat == 1) ? Wk : Wv;
#pragma unroll
    for (int i = 0; i < 8; ++i) {
      int idx = i * 256 + tid;          // 0..2047
      int c = idx >> 4, ch = idx & 15;
      int h = c >> 5, k = c & 31;
      union { unsigned short s[8]; uint4 v; } u;
#pragma unroll
      for (int j = 0; j < 8; ++j) {
        int d = ch * 8 + j;
        u.s[j] = f2b(W[(size_t)((h * 3 + t) * 128 + d) * 32 + k]);
      }
      *(uint4*)&Wt[(size_t)b * 16384 + c * 128 + ch * 8] = u.v;
    }
  } else if (b < 5009) {
    const int r = (b - 9) * 8 + (tid >> 5);   // 8 rows/block, 32 lanes/row
    const int l32 = tid & 31;
    float4 v = *(const float4*)(x + (size_t)r * DD + l32 * 4);
    float s  = v.x + v.y + v.z + v.w;
    float ss = v.x * v.x + v.y * v.y + v.z * v.z + v.w * v.w;
#pragma unroll
    for (int off = 1; off < 32; off <<= 1) { s += __shfl_xor(s, off); ss += __shfl_xor(ss, off); }
    float mu = s * (1.f / 128.f);
    float rs = rsqrtf(ss * (1.f / 128.f) - mu * mu + 1e-5f);
    float4 g = *(const float4*)(gamma + l32 * 4);
    float4 bb = *(const float4*)(beta + l32 * 4);
    ushort4 o;
    o.x = f2b((v.x - mu) * rs * g.x + bb.x);
    o.y = f2b((v.y - mu) * rs * g.y + bb.y);
    o.z = f2b((v.z - mu) * rs * g.z + bb.z);
    o.w = f2b((v.w - mu) * rs * g.w + bb.w);
    *(ushort4*)(Xn + (size_t)r * DD + l32 * 4) = o;
  } else {
    int e = (b - 5009) * 256 + tid;
    rank[e] = atomicAdd(&deg[ei[NE + e]], 1);
  }
}

// ---------------------------------------------------------------
// QKV projection, bf16 MFMA. grid (9, 625), block 256 (4 waves).
// 64-row x 128-col tile per block; wave w owns rows w*16..+15.
// Q -> Qo [t*NN+n][128]; K/V -> KVo interleaved [t*NN+n][256] (K:0-127, V:128-255).
// ---------------------------------------------------------------
__global__ __launch_bounds__(256)
void qkv_kernel(const unsigned short* __restrict__ Xn,
                const float* __restrict__ bq, const float* __restrict__ bk,
                const float* __restrict__ bv,
                const unsigned short* __restrict__ Wt,
                unsigned short* __restrict__ Qo, unsigned short* __restrict__ KVo)
{
  __shared__ unsigned char xs[16384];  // 64 rows x 256B (swizzled)
  __shared__ unsigned char wt[32768];  // 128 c-rows x 256B (swizzled)
  const int tid = threadIdx.x;
  const int lane = tid & 63;
  const int w = tid >> 6;
  const int l15 = lane & 15, kh = lane >> 4;
  const int combo = blockIdx.x;
  const int n0 = blockIdx.y * 64;
  const int mat = combo / 3, t = combo % 3;
  const float* B = (mat == 0) ? bq : (mat == 1) ? bk : bv;
  unsigned short* O; int ostride;
  if (mat == 0)      { O = Qo;        ostride = 128; }
  else if (mat == 1) { O = KVo;       ostride = 256; }
  else               { O = KVo + 128; ostride = 256; }

  // ---- stage Wt slab (32KB) ----
#pragma unroll
  for (int i = 0; i < 8; ++i) {
    int idx = i * 256 + tid;
    int rr = idx >> 4, ch = idx & 15;
    uint4 d4 = *(const uint4*)(Wt + (size_t)combo * 16384 + rr * 128 + ch * 8);
    *(uint4*)(wt + swz(rr * 256 + ch * 16)) = d4;
  }
  // ---- stage Xn tile (16KB) ----
#pragma unroll
  for (int i = 0; i < 4; ++i) {
    int idx = i * 256 + tid;
    int rr = idx >> 4, ch = idx & 15;
    uint4 d4 = *(const uint4*)(Xn + (size_t)(n0 + rr) * DD + ch * 8);
    *(uint4*)(xs + swz(rr * 256 + ch * 16)) = d4;
  }

  // ---- init acc with bias ----
  f32x4 acc[8];
#pragma unroll
  for (int ct = 0; ct < 8; ++ct) {
    int cc = ct * 16 + l15;
    float bb = B[((cc >> 5) * 3 + t) * 32 + (cc & 31)];
    f32x4 bi = {bb, bb, bb, bb};
    acc[ct] = bi;
  }
  __syncthreads();

  // ---- MFMA: 4 k-steps x 8 col-tiles ----
#pragma unroll
  for (int ks = 0; ks < 4; ++ks) {
    short8 a0 = *(const short8*)(xs + swz((w * 16 + l15) * 256 + ks * 64 + kh * 16));
#pragma unroll
    for (int ct = 0; ct < 8; ++ct) {
      short8 bf = *(const short8*)(wt + swz((ct * 16 + l15) * 256 + ks * 64 + kh * 16));
      acc[ct] = __builtin_amdgcn_mfma_f32_16x16x32_bf16(a0, bf, acc[ct], 0, 0, 0);
    }
  }

  // ---- epilogue: repack own rows via LDS (wave-private region) ----
#pragma unroll
  for (int ct = 0; ct < 8; ++ct)
#pragma unroll
    for (int rg = 0; rg < 4; ++rg) {
      int rr = w * 16 + kh * 4 + rg;
      int cc = ct * 16 + l15;
      *(unsigned short*)(xs + swz(rr * 256 + cc * 2)) = f2b(acc[ct][rg]);
    }
  __syncthreads();
#pragma unroll
  for (int i = 0; i < 4; ++i) {
    int idx = i * 256 + tid;
    int rr = idx >> 4, ch = idx & 15;
    uint4 d4 = *(const uint4*)(xs + swz(rr * 256 + ch * 16));
    *(uint4*)(O + ((size_t)t * NN + n0 + rr) * ostride + ch * 8) = d4;
  }
}

// ---- two-level scan: part + (mid+add fused) ----
__global__ __launch_bounds__(256)
void scan_part(const int* __restrict__ deg, int* __restrict__ base, int* __restrict__ bsum)
{
  const int b = blockIdx.x, tid = threadIdx.x;
  int i = b * 256 + tid;
  int v = (i < NN) ? deg[i] : 0;
  int xv = v;
#pragma unroll
  for (int off = 1; off < 64; off <<= 1) {
    int y = __shfl_up(xv, off);
    if ((tid & 63) >= off) xv += y;
  }
  __shared__ int wsum[4];
  if ((tid & 63) == 63) wsum[tid >> 6] = xv;
  __syncthreads();
  int add = 0;
  if (tid >= 64)  add += wsum[0];
  if (tid >= 128) add += wsum[1];
  if (tid >= 192) add += wsum[2];
  xv += add;
  if (i < NN) base[i] = xv - v;   // local exclusive
  if (tid == 255) bsum[b] = xv;
}

// Each block sums bsum[i < blockIdx.x] (157 values) and adds to its chunk.
__global__ __launch_bounds__(256)
void scan_fin(int* __restrict__ base, const int* __restrict__ bsum)
{
  const int b = blockIdx.x, tid = threadIdx.x;
  int v = (tid < b && tid < 157) ? bsum[tid] : 0;
#pragma unroll
  for (int off = 1; off < 64; off <<= 1) v += __shfl_xor(v, off);
  __shared__ int ws4[4];
  if ((tid & 63) == 0) ws4[tid >> 6] = v;
  __syncthreads();
  int boff = ws4[0] + ws4[1] + ws4[2] + ws4[3];
  int i = b * 256 + tid;
  if (i < NN) base[i] += boff;
  if (b == 0 && tid == 0) base[NN] = NE;
}

// ---------------------------------------------------------------
// Scatter edges into CSR slots (no atomics: slot = base[dst] + rank[e]).
// esl[slot] = { src | t<<16, bits(decay) }.
// ---------------------------------------------------------------
__global__ __launch_bounds__(256)
void scatter_kernel(const int* __restrict__ ei, const float* __restrict__ ev,
                    const float* __restrict__ m1, const float* __restrict__ m2,
                    const int* __restrict__ base, const int* __restrict__ rank,
                    int2* __restrict__ esl)
{
  int e = blockIdx.x * 256 + threadIdx.x;
  int src = ei[e];
  int dst = ei[NE + e];
  int t = (m1[e] > 0.5f) ? 1 : ((m2[e] > 0.5f) ? 2 : 0);
  float av = fabsf(ev[e]);
  float decay = exp2f(-0.15200309344504995f * av);      // 0.9^|v|
  int slot = base[dst] + rank[e];
  int2 v; v.x = src | (t << 16); v.y = __float_as_int(decay);
  esl[slot] = v;
}

// ---------------------------------------------------------------
// Fused per-node attention, wave-synchronous, unified 16-lane-per-edge
// layout: lane l15 owns comps l15*8..+8, all within head l15>>2.
//   - QK dot: 4-pair partial per lane + quad reduce (shfl_xor 1,2 = DPP).
//   - exp/a is then LANE-LOCAL for the V FMA: no inter-phase shuffles.
//   - den += a per lane; final shfl_xor(16,32) completes acc AND den.
// 4 edges in flight (4 groups) x2 unroll = 8 concurrent edge pipelines.
// Branchless (clamped slot); padding edges carry weight 0.
// Softmax without max-shift (scores bounded; global shift cancels to ~1e-10).
// ---------------------------------------------------------------
__global__ __launch_bounds__(256)
void agg_kernel(const float* __restrict__ x,
                const unsigned short* __restrict__ Q,
                const unsigned short* __restrict__ KV,
                const int2* __restrict__ esl, const int* __restrict__ base,
                float* __restrict__ out)
{
  const int l = threadIdx.x & 63;
  const int n = blockIdx.x * 4 + (threadIdx.x >> 6);
  const int b0 = base[n], b1 = base[n + 1];
  const int g = l >> 4, l15 = l & 15;      // group, lane-in-group
  float acc[8] = {0.f, 0.f, 0.f, 0.f, 0.f, 0.f, 0.f, 0.f};
  float den = 0.f;

  const int last = b1 - 1;
  for (int cs = b0; cs < b1; cs += 8) {
    // ---- edge A: slot cs + g ----
    int jA = cs + g;
    bool actA = (jA < b1);
    int2 ecA = esl[actA ? jA : last];
    int srcA = ecA.x & 0xFFFF, tA = ecA.x >> 16;
    const unsigned short* krA = KV + ((size_t)tA * NN + srcA) * 256;
    const unsigned short* qrA = Q + ((size_t)tA * NN + n) * DD;
    uint4 kA = *(const uint4*)(krA + l15 * 8);
    uint4 qA = *(const uint4*)(qrA + l15 * 8);
    uint4 vA = *(const uint4*)(krA + 128 + l15 * 8);
    // ---- edge B: slot cs + 4 + g ----
    int jB = cs + 4 + g;
    bool actB = (jB < b1);
    int2 ecB = esl[actB ? jB : last];
    int srcB = ecB.x & 0xFFFF, tB = ecB.x >> 16;
    const unsigned short* krB = KV + ((size_t)tB * NN + srcB) * 256;
    const unsigned short* qrB = Q + ((size_t)tB * NN + n) * DD;
    uint4 kB = *(const uint4*)(krB + l15 * 8);
    uint4 qB = *(const uint4*)(qrB + l15 * 8);
    uint4 vB = *(const uint4*)(krB + 128 + l15 * 8);

    float dA = pdot(kA.x, qA.x) + pdot(kA.y, qA.y) + pdot(kA.z, qA.z) + pdot(kA.w, qA.w);
    float dB = pdot(kB.x, qB.x) + pdot(kB.y, qB.y) + pdot(kB.z, qB.z) + pdot(kB.w, qB.w);
    // quad-local reduce: full head-dot in every lane (DPP-cheap)
    dA += __shfl_xor(dA, 1);  dA += __shfl_xor(dA, 2);
    dB += __shfl_xor(dB, 1);  dB += __shfl_xor(dB, 2);
    float aA = __expf(dA * 0.17677669529663687f * __int_as_float(ecA.y));
    float aB = __expf(dB * 0.17677669529663687f * __int_as_float(ecB.y));
    aA = actA ? aA : 0.f;
    aB = actB ? aB : 0.f;
    den += aA + aB;
    acc[0] += aA * blo(vA.x) + aB * blo(vB.x);
    acc[1] += aA * bhi(vA.x) + aB * bhi(vB.x);
    acc[2] += aA * blo(vA.y) + aB * blo(vB.y);
    acc[3] += aA * bhi(vA.y) + aB * bhi(vB.y);
    acc[4] += aA * blo(vA.z) + aB * blo(vB.z);
    acc[5] += aA * bhi(vA.z) + aB * bhi(vB.z);
    acc[6] += aA * blo(vA.w) + aB * blo(vB.w);
    acc[7] += aA * bhi(vA.w) + aB * bhi(vB.w);
  }

  // cross-group combine: sums the 4 groups for acc AND den (lane keeps l15)
#pragma unroll
  for (int k2 = 0; k2 < 8; ++k2) {
    acc[k2] += __shfl_xor(acc[k2], 16);
    acc[k2] += __shfl_xor(acc[k2], 32);
  }
  den += __shfl_xor(den, 16);
  den += __shfl_xor(den, 32);
  float dh = den + 1e-16f;     // lane's den IS its head's denom
  if (g == 0) {
    const float* xr = x + (size_t)n * DD + l15 * 8;
    float4 x0 = *(const float4*)xr;
    float4 x1 = *(const float4*)(xr + 4);
    float z[8];
#pragma unroll
    for (int k2 = 0; k2 < 8; ++k2) {
      float zz = acc[k2] / dh;
      z[k2] = 0.5f * zz * (1.0f + erff(zz * 0.70710678118654752f));
    }
    float4 o0 = make_float4(x0.x + z[0], x0.y + z[1], x0.z + z[2], x0.w + z[3]);
    float4 o1 = make_float4(x1.x + z[4], x1.y + z[5], x1.z + z[6], x1.w + z[7]);
    float* po = out + (size_t)n * DD + l15 * 8;
    *(float4*)po = o0;
    *(float4*)(po + 4) = o1;
  }
}

// ---------------------------------------------------------------
extern "C" void kernel_launch(void* const* d_in, const int* in_sizes, int n_in,
                              void* d_out, int out_size, void* d_ws, size_t ws_size,
                              hipStream_t stream)
{
  const float* x     = (const float*)d_in[0];
  const int*   ei    = (const int*)d_in[1];
  const float* ev    = (const float*)d_in[2];
  const float* m1    = (const float*)d_in[5];  // diff_time_same_var -> t=1
  const float* m2    = (const float*)d_in[6];  // diff_time_diff_var -> t=2
  const float* gamma = (const float*)d_in[8];
  const float* beta  = (const float*)d_in[9];
  const float* Wq    = (const float*)d_in[10];
  const float* bq    = (const float*)d_in[11];
  const float* Wk    = (const float*)d_in[12];
  const float* bk    = (const float*)d_in[13];
  const float* Wv    = (const float*)d_in[14];
  const float* bv    = (const float*)d_in[15];
  float* out = (float*)d_out;

  // ---- workspace layout ----
  unsigned short* Q  = (unsigned short*)d_ws;        // 3*NN*128 bf16
  unsigned short* KV = Q  + (size_t)3 * NN * DD;     // 3*NN*256 bf16 (K|V interleaved)
  unsigned short* Xn = KV + (size_t)3 * NN * 256;    // NN*128 bf16
  unsigned short* Wt = Xn + (size_t)NN * DD;         // 9*16384 bf16
  int2*  esl  = (int2*)(Wt + 9 * 16384);             // NE int2 (8B-aligned)
  int*   rank = (int*)(esl + NE);                    // NE
  int*   deg  = rank + NE;                           // NN
  int*   base = deg + NN;                            // NN+1
  int*   bsum = base + NN + 1;                       // 157

  hipMemsetAsync(deg, 0, (size_t)NN * sizeof(int), stream);  // deg only

  prep_kernel<<<7509, 256, 0, stream>>>(Wq, Wk, Wv, Wt, x, gamma, beta, Xn, ei, deg, rank);
  qkv_kernel<<<dim3(9, NN / 64), 256, 0, stream>>>(Xn, bq, bk, bv, Wt, Q, KV);
  scan_part<<<157, 256, 0, stream>>>(deg, base, bsum);
  scan_fin<<<157, 256, 0, stream>>>(base, bsum);
  scatter_kernel<<<NE / 256, 256, 0, stream>>>(ei, ev, m1, m2, base, rank, esl);
  agg_kernel<<<NN / 4, 256, 0, stream>>>(x, Q, KV, esl, base, out);
}